// Round 5
// baseline (530.360 us; speedup 1.0000x reference)
//
#include <hip/hip_runtime.h>

typedef __bf16 bf16_t;
typedef __bf16 bf16x8 __attribute__((ext_vector_type(8)));
typedef __bf16 bf16x4 __attribute__((ext_vector_type(4)));
typedef float f32x4 __attribute__((ext_vector_type(4)));

#define DM 768
#define SEQ_LEN 4096
#define TOKENS 32768

// async 16B global -> LDS (wave-uniform LDS base + lane*16)
__device__ __forceinline__ void load16_to_lds(const void* g, void* l) {
  __builtin_amdgcn_global_load_lds(
      (const __attribute__((address_space(1))) unsigned int*)g,
      (__attribute__((address_space(3))) unsigned int*)l, 16, 0, 0);
}

// ---------------- weight cast / transpose ----------------
__global__ __launch_bounds__(256)
void cast_transpose_kernel(const float* __restrict__ W, bf16_t* __restrict__ WT,
                           int K, int N, int stride, int off) {
  long idx = (long)blockIdx.x * 256 + threadIdx.x;
  if (idx >= (long)K * N) return;
  int n = (int)(idx / K);
  int k = (int)(idx % K);
  WT[idx] = (bf16_t)W[(long)k * stride + off + n];
}

// a[k] = -sum_d exp(A_log[k,d]) ; b[k] = sum_{d<16} W_x[k,d]
__global__ __launch_bounds__(256)
void ab_kernel(const float* __restrict__ Wx, const float* __restrict__ A_log,
               float* __restrict__ a_vec, float* __restrict__ b_vec) {
  int k = blockIdx.x * 256 + threadIdx.x;
  if (k >= DM) return;
  float a = 0.f, b = 0.f;
#pragma unroll
  for (int d = 0; d < 16; d++) {
    a -= __expf(A_log[k * 16 + d]);
    b += Wx[(long)k * 784 + d];
  }
  a_vec[k] = a;
  b_vec[k] = b;
}

// ---------------- layernorm -> bf16 (token per wave, float4) ----------------
__global__ __launch_bounds__(256)
void ln_kernel(const float* __restrict__ x, const float* __restrict__ gamma,
               const float* __restrict__ beta, bf16_t* __restrict__ xn) {
  const int tok = blockIdx.x * 4 + (threadIdx.x >> 6);
  const int lane = threadIdx.x & 63;
  const float4* xr = (const float4*)(x + (long)tok * DM);
  float4 v0 = xr[lane], v1 = xr[lane + 64], v2 = xr[lane + 128];
  float s = v0.x + v0.y + v0.z + v0.w + v1.x + v1.y + v1.z + v1.w +
            v2.x + v2.y + v2.z + v2.w;
  float ss = v0.x * v0.x + v0.y * v0.y + v0.z * v0.z + v0.w * v0.w +
             v1.x * v1.x + v1.y * v1.y + v1.z * v1.z + v1.w * v1.w +
             v2.x * v2.x + v2.y * v2.y + v2.z * v2.z + v2.w * v2.w;
  for (int o = 1; o < 64; o <<= 1) { s += __shfl_xor(s, o); ss += __shfl_xor(ss, o); }
  float mu = s * (1.0f / DM);
  float var = ss * (1.0f / DM) - mu * mu;
  float inv = rsqrtf(var + 1e-5f);
  const float4* g4 = (const float4*)gamma;
  const float4* b4 = (const float4*)beta;
  bf16_t* xo = xn + (long)tok * DM;
#pragma unroll
  for (int i = 0; i < 3; i++) {
    float4 v = (i == 0) ? v0 : (i == 1) ? v1 : v2;
    float4 g = g4[lane + 64 * i], b = b4[lane + 64 * i];
    bf16x4 o;
    o[0] = (bf16_t)((v.x - mu) * inv * g.x + b.x);
    o[1] = (bf16_t)((v.y - mu) * inv * g.y + b.y);
    o[2] = (bf16_t)((v.z - mu) * inv * g.z + b.z);
    o[3] = (bf16_t)((v.w - mu) * inv * g.w + b.w);
    *(bf16x4*)(xo + lane * 4 + i * 256) = o;
  }
}

// ---------------- depthwise causal conv (4 taps) + hs (token per wave) -------
__global__ __launch_bounds__(256)
void conv_kernel(const bf16_t* __restrict__ xz, const float* __restrict__ conv_w,
                 const float* __restrict__ a_vec, const float* __restrict__ b_vec,
                 bf16_t* __restrict__ x1, float* __restrict__ hs) {
  const int tok = blockIdx.x * 4 + (threadIdx.x >> 6);
  const int lane = threadIdx.x & 63;
  const int l = tok & (SEQ_LEN - 1);
  const bf16_t* base = xz + (long)tok * 1536;
  const float4* w4 = (const float4*)conv_w;
  float s = 0.f, sa = 0.f, sb = 0.f;

  {
    const int c0 = lane * 8;
    bf16x8 cur = *(const bf16x8*)(base + c0);
    bf16x8 p1 = {}, p2 = {}, p3 = {};
    if (l >= 1) p1 = *(const bf16x8*)(base + c0 - 1536);
    if (l >= 2) p2 = *(const bf16x8*)(base + c0 - 2 * 1536);
    if (l >= 3) p3 = *(const bf16x8*)(base + c0 - 3 * 1536);
    bf16x8 o;
#pragma unroll
    for (int j = 0; j < 8; j++) {
      float4 w = w4[c0 + j];
      float acc = w.w * (float)cur[j] + w.z * (float)p1[j] +
                  w.y * (float)p2[j] + w.x * (float)p3[j];
      bf16_t xb = (bf16_t)acc;
      o[j] = xb;
      float xv = (float)xb;
      s += xv; sa += xv * a_vec[c0 + j]; sb += xv * b_vec[c0 + j];
    }
    *(bf16x8*)(x1 + (long)tok * DM + c0) = o;
  }
  {
    const int c0 = 512 + lane * 4;
    bf16x4 cur = *(const bf16x4*)(base + c0);
    bf16x4 p1 = {}, p2 = {}, p3 = {};
    if (l >= 1) p1 = *(const bf16x4*)(base + c0 - 1536);
    if (l >= 2) p2 = *(const bf16x4*)(base + c0 - 2 * 1536);
    if (l >= 3) p3 = *(const bf16x4*)(base + c0 - 3 * 1536);
    bf16x4 o;
#pragma unroll
    for (int j = 0; j < 4; j++) {
      float4 w = w4[c0 + j];
      float acc = w.w * (float)cur[j] + w.z * (float)p1[j] +
                  w.y * (float)p2[j] + w.x * (float)p3[j];
      bf16_t xb = (bf16_t)acc;
      o[j] = xb;
      float xv = (float)xb;
      s += xv; sa += xv * a_vec[c0 + j]; sb += xv * b_vec[c0 + j];
    }
    *(bf16x4*)(x1 + (long)tok * DM + c0) = o;
  }
  for (int o = 1; o < 64; o <<= 1) {
    s += __shfl_xor(s, o); sa += __shfl_xor(sa, o); sb += __shfl_xor(sb, o);
  }
  if (lane == 0) hs[tok] = sa + s * sb;
}

// ================= 256x256 8-phase MFMA GEMM (T2+T3+T4+T5) =================
// C[M,N] = A[M,K] @ BT[N,K]^T. 512 thr / 8 waves (2M x 4N), wave-tile 128x64,
// acc 8x4 of 16x16x32. BK=64, 2 K-tiles per loop iteration, 8 phases.
// LDS 128 KB: A/B row-major [256][64] bf16, XOR-swizzled 16B slots
// (s_phys = s_log ^ (row&7)); staging keeps linear LDS dest and pre-swizzles
// the per-lane GLOBAL source column (rule: both-sides-or-neither).
// Sync proof: stage into buf b is issued only >=1 barrier after the phase
// containing the last ds_read of b (P4->P5 / P8->P1 boundaries), and each
// buffer's reads begin only after vmcnt(0)+barrier drains its stage loads.
template <int OUT_MODE>
__global__ __launch_bounds__(512, 2)
void gemm256_kernel(const bf16_t* __restrict__ A, const bf16_t* __restrict__ BT,
                    void* __restrict__ outp, const float* __restrict__ res,
                    const bf16_t* __restrict__ x1, const bf16_t* __restrict__ xz,
                    const float* __restrict__ hs, const float* __restrict__ Dp,
                    int M, int N, int K) {
  __shared__ __align__(16) bf16_t As[2][256 * 64];  // 64 KB
  __shared__ __align__(16) bf16_t Bs[2][256 * 64];  // 64 KB

  const int nby = N >> 8;                     // N/256
  const int nwg = (M >> 8) * nby;
  const int cpx = nwg >> 3;
  const int wg = blockIdx.x;
  const int swz = (wg & 7) * cpx + (wg >> 3); // bijective (nwg % 8 == 0)
  const int bx = swz / nby;
  const int by = swz - bx * nby;
  const int m0 = bx << 8;
  const int n0 = by << 8;

  const int t = threadIdx.x;
  const int lane = t & 63;
  const int wave = t >> 6;                    // 0..7
  const int wm = (wave >> 2) * 128;           // 0 or 128
  const int wn = (wave & 3) * 64;             // 0,64,128,192
  const int l15 = lane & 15;
  const int quad = lane >> 4;

  // swizzled k-slot offsets for ds_read (elements). row&7 == lane&7 for all
  // fragment rows (all row-bases are multiples of 8).
  const int sx0 = (((0 * 4) + quad) ^ (lane & 7)) * 8;
  const int sx1 = (((1 * 4) + quad) ^ (lane & 7)) * 8;

  // staging: lane covers row (chunkbase + lane>>3), logical k-slot
  // (lane&7)^((lane>>3)&7)  (chunk bases are multiples of 8 rows).
  const int srow = lane >> 3;
  const int scol = (((lane & 7) ^ ((lane >> 3) & 7))) * 8;

  f32x4 acc[8][4] = {};
  bf16x8 a[4][2], b0[2][2], b1[2][2];

  const bf16_t* Abase = A + (long)m0 * K + scol;
  const bf16_t* Bbase = BT + (long)n0 * K + scol;

#define STAGE_A(buf, kt) do {                                               \
    const long kk_ = (long)(kt) * 64;                                       \
    _Pragma("unroll")                                                       \
    for (int h_ = 0; h_ < 2; h_++) {                                        \
      _Pragma("unroll")                                                     \
      for (int j_ = 0; j_ < 2; j_++) {                                      \
        const int rowl_ = h_ * 128 + wave * 16 + j_ * 8;                    \
        load16_to_lds(Abase + (long)(rowl_ + srow) * K + kk_,               \
                      &As[buf][rowl_ * 64]);                                \
      } } } while (0)

#define STAGE_B(buf, kt) do {                                               \
    const long kk_ = (long)(kt) * 64;                                       \
    _Pragma("unroll")                                                       \
    for (int h_ = 0; h_ < 2; h_++) {                                        \
      _Pragma("unroll")                                                     \
      for (int j_ = 0; j_ < 2; j_++) {                                      \
        const int rowl_ = h_ * 128 + wave * 16 + j_ * 8;                    \
        load16_to_lds(Bbase + (long)(rowl_ + srow) * K + kk_,               \
                      &Bs[buf][rowl_ * 64]);                                \
      } } } while (0)

#define READ_A(qm, buf) do {                                                \
    _Pragma("unroll")                                                       \
    for (int mi_ = 0; mi_ < 4; mi_++) {                                     \
      const bf16_t* p_ = &As[buf][(wm + (qm) * 64 + mi_ * 16 + l15) * 64];  \
      a[mi_][0] = *(const bf16x8*)(p_ + sx0);                               \
      a[mi_][1] = *(const bf16x8*)(p_ + sx1);                               \
    } } while (0)

#define READ_B(dst, qn, buf) do {                                           \
    _Pragma("unroll")                                                       \
    for (int ni_ = 0; ni_ < 2; ni_++) {                                     \
      const bf16_t* p_ = &Bs[buf][(wn + (qn) * 32 + ni_ * 16 + l15) * 64];  \
      dst[ni_][0] = *(const bf16x8*)(p_ + sx0);                             \
      dst[ni_][1] = *(const bf16x8*)(p_ + sx1);                             \
    } } while (0)

#define MFMA16(qm, qn, breg) do {                                           \
    __builtin_amdgcn_s_setprio(1);                                          \
    _Pragma("unroll")                                                       \
    for (int mi_ = 0; mi_ < 4; mi_++) {                                     \
      _Pragma("unroll")                                                     \
      for (int ni_ = 0; ni_ < 2; ni_++) {                                   \
        acc[(qm) * 4 + mi_][(qn) * 2 + ni_] =                               \
            __builtin_amdgcn_mfma_f32_16x16x32_bf16(                        \
                a[mi_][0], breg[ni_][0],                                    \
                acc[(qm) * 4 + mi_][(qn) * 2 + ni_], 0, 0, 0);              \
        acc[(qm) * 4 + mi_][(qn) * 2 + ni_] =                               \
            __builtin_amdgcn_mfma_f32_16x16x32_bf16(                        \
                a[mi_][1], breg[ni_][1],                                    \
                acc[(qm) * 4 + mi_][(qn) * 2 + ni_], 0, 0, 0);              \
      } }                                                                   \
    __builtin_amdgcn_s_setprio(0);                                          \
  } while (0)

#define BAR() do { asm volatile("" ::: "memory");                           \
    __builtin_amdgcn_s_barrier();                                           \
    asm volatile("" ::: "memory"); } while (0)

#define VM0() asm volatile("s_waitcnt vmcnt(0)" ::: "memory")

  const int NT = K >> 6;   // K/64 K-tiles (12 for K=768)
  const int NI = NT >> 1;  // loop iterations, 2 K-tiles each

  // prologue: stage K-tile 0 into buf0
  STAGE_A(0, 0);
  STAGE_B(0, 0);
  VM0();
  BAR();

  for (int it = 0; it < NI; ++it) {
    const int t1k = 2 * it + 1;  // -> buf1 (free since prev P8 gate)
    const int t2k = 2 * it + 2;  // -> buf0 (free after P4 gate)
    // ---- phases 1-4: K-tile 2it from buf0 ----
    STAGE_A(1, t1k);            // P1
    READ_A(0, 0);
    READ_B(b0, 0, 0);
    MFMA16(0, 0, b0);
    BAR();
    STAGE_B(1, t1k);            // P2
    READ_B(b1, 1, 0);
    MFMA16(0, 1, b1);
    BAR();
    READ_A(1, 0);               // P3
    MFMA16(1, 1, b1);
    BAR();
    MFMA16(1, 0, b0);           // P4
    VM0();                      // all t1k stages landed (issued P1/P2)
    BAR();
    // ---- phases 5-8: K-tile 2it+1 from buf1 ----
    if (t2k < NT) STAGE_A(0, t2k);  // P5 (buf0 reads ended at P4)
    READ_A(0, 1);
    READ_B(b0, 0, 1);
    MFMA16(0, 0, b0);
    BAR();
    if (t2k < NT) STAGE_B(0, t2k);  // P6
    READ_B(b1, 1, 1);
    MFMA16(0, 1, b1);
    BAR();
    READ_A(1, 1);               // P7
    MFMA16(1, 1, b1);
    BAR();
    MFMA16(1, 0, b0);           // P8
    VM0();                      // all t2k stages landed before next P1 reads
    BAR();
  }

  // -------- epilogue --------
#pragma unroll
  for (int mi = 0; mi < 8; mi++) {
#pragma unroll
    for (int r = 0; r < 4; r++) {
      const int row = m0 + wm + mi * 16 + quad * 4 + r;
      float hsv = 0.f;
      if (OUT_MODE == 1) hsv = hs[row];
#pragma unroll
      for (int ni = 0; ni < 4; ni++) {
        const int col = n0 + wn + ni * 16 + l15;
        const long o = (long)row * N + col;
        float v = acc[mi][ni][r];
        if (OUT_MODE == 0) {
          ((bf16_t*)outp)[o] = (bf16_t)v;
        } else if (OUT_MODE == 1) {
          float xv = (float)x1[(long)row * DM + col];
          float zv = (float)xz[(long)row * 1536 + DM + col];
          float yv = v * hsv + Dp[col] * xv;
          yv *= zv / (1.f + __expf(-zv));
          ((bf16_t*)outp)[o] = (bf16_t)yv;
        } else {
          ((float*)outp)[o] = v + res[o];
        }
      }
    }
  }
#undef STAGE_A
#undef STAGE_B
#undef READ_A
#undef READ_B
#undef MFMA16
#undef BAR
#undef VM0
}

// ---------------- launch ----------------
extern "C" void kernel_launch(void* const* d_in, const int* in_sizes, int n_in,
                              void* d_out, int out_size, void* d_ws, size_t ws_size,
                              hipStream_t stream) {
  const float* x      = (const float*)d_in[0];
  const float* W_in   = (const float*)d_in[1];
  const float* conv_w = (const float*)d_in[2];
  const float* W_x    = (const float*)d_in[3];
  const float* A_log  = (const float*)d_in[4];
  const float* Dp     = (const float*)d_in[5];
  const float* W_out  = (const float*)d_in[6];
  const float* gamma  = (const float*)d_in[7];
  const float* beta   = (const float*)d_in[8];
  float* out = (float*)d_out;

  char* ws = (char*)d_ws;
  bf16_t* w_in_T  = (bf16_t*)(ws + 0);          // 1536x768 bf16
  bf16_t* w_c_T   = (bf16_t*)(ws + 2359296);    //  768x768 bf16
  bf16_t* w_out_T = (bf16_t*)(ws + 3538944);    //  768x768 bf16
  float*  a_vec   = (float*)(ws + 4718592);
  float*  b_vec   = (float*)(ws + 4721664);
  float*  hs      = (float*)(ws + 4724736);     // 32768 f32
  bf16_t* xn      = (bf16_t*)(ws + 4855808);    // 32768x768 bf16 (reused as y)
  bf16_t* xz      = (bf16_t*)(ws + 55187456);   // 32768x1536 bf16
  bf16_t* x1      = (bf16_t*)(ws + 155850752);  // 32768x768 bf16
  bf16_t* y       = xn;

  cast_transpose_kernel<<<dim3(1536 * 768 / 256), 256, 0, stream>>>(W_in, w_in_T, 768, 1536, 1536, 0);
  cast_transpose_kernel<<<dim3(768 * 768 / 256), 256, 0, stream>>>(W_x, w_c_T, 768, 768, 784, 16);
  cast_transpose_kernel<<<dim3(768 * 768 / 256), 256, 0, stream>>>(W_out, w_out_T, 768, 768, 768, 0);
  ab_kernel<<<dim3(3), 256, 0, stream>>>(W_x, A_log, a_vec, b_vec);

  ln_kernel<<<dim3(TOKENS / 4), 256, 0, stream>>>(x, gamma, beta, xn);

  gemm256_kernel<0><<<dim3((TOKENS / 256) * (1536 / 256)), 512, 0, stream>>>(
      xn, w_in_T, (void*)xz, nullptr, nullptr, nullptr, nullptr, nullptr,
      TOKENS, 1536, 768);

  conv_kernel<<<dim3(TOKENS / 4), 256, 0, stream>>>(xz, conv_w, a_vec, b_vec, x1, hs);

  gemm256_kernel<1><<<dim3((TOKENS / 256) * (768 / 256)), 512, 0, stream>>>(
      x1, w_c_T, (void*)y, nullptr, x1, xz, hs, Dp,
      TOKENS, 768, 768);

  gemm256_kernel<2><<<dim3((TOKENS / 256) * (768 / 256)), 512, 0, stream>>>(
      y, w_out_T, (void*)out, x, nullptr, nullptr, nullptr, nullptr,
      TOKENS, 768, 768);
}

// Round 6
// 511.337 us; speedup vs baseline: 1.0372x; 1.0372x over previous
//
#include <hip/hip_runtime.h>

typedef __bf16 bf16_t;
typedef __bf16 bf16x8 __attribute__((ext_vector_type(8)));
typedef __bf16 bf16x4 __attribute__((ext_vector_type(4)));
typedef float f32x4 __attribute__((ext_vector_type(4)));

#define DM 768
#define SEQ_LEN 4096
#define TOKENS 32768

// async 16B global -> LDS (wave-uniform LDS base + lane*16)
__device__ __forceinline__ void load16_to_lds(const void* g, void* l) {
  __builtin_amdgcn_global_load_lds(
      (const __attribute__((address_space(1))) unsigned int*)g,
      (__attribute__((address_space(3))) unsigned int*)l, 16, 0, 0);
}

// ---------------- weight cast / transpose ----------------
__global__ __launch_bounds__(256)
void cast_transpose_kernel(const float* __restrict__ W, bf16_t* __restrict__ WT,
                           int K, int N, int stride, int off) {
  long idx = (long)blockIdx.x * 256 + threadIdx.x;
  if (idx >= (long)K * N) return;
  int n = (int)(idx / K);
  int k = (int)(idx % K);
  WT[idx] = (bf16_t)W[(long)k * stride + off + n];
}

// a[k] = -sum_d exp(A_log[k,d]) ; b[k] = sum_{d<16} W_x[k,d]
__global__ __launch_bounds__(256)
void ab_kernel(const float* __restrict__ Wx, const float* __restrict__ A_log,
               float* __restrict__ a_vec, float* __restrict__ b_vec) {
  int k = blockIdx.x * 256 + threadIdx.x;
  if (k >= DM) return;
  float a = 0.f, b = 0.f;
#pragma unroll
  for (int d = 0; d < 16; d++) {
    a -= __expf(A_log[k * 16 + d]);
    b += Wx[(long)k * 784 + d];
  }
  a_vec[k] = a;
  b_vec[k] = b;
}

// ---------------- layernorm -> bf16 (token per wave, float4) ----------------
__global__ __launch_bounds__(256)
void ln_kernel(const float* __restrict__ x, const float* __restrict__ gamma,
               const float* __restrict__ beta, bf16_t* __restrict__ xn) {
  const int tok = blockIdx.x * 4 + (threadIdx.x >> 6);
  const int lane = threadIdx.x & 63;
  const float4* xr = (const float4*)(x + (long)tok * DM);
  float4 v0 = xr[lane], v1 = xr[lane + 64], v2 = xr[lane + 128];
  float s = v0.x + v0.y + v0.z + v0.w + v1.x + v1.y + v1.z + v1.w +
            v2.x + v2.y + v2.z + v2.w;
  float ss = v0.x * v0.x + v0.y * v0.y + v0.z * v0.z + v0.w * v0.w +
             v1.x * v1.x + v1.y * v1.y + v1.z * v1.z + v1.w * v1.w +
             v2.x * v2.x + v2.y * v2.y + v2.z * v2.z + v2.w * v2.w;
  for (int o = 1; o < 64; o <<= 1) { s += __shfl_xor(s, o); ss += __shfl_xor(ss, o); }
  float mu = s * (1.0f / DM);
  float var = ss * (1.0f / DM) - mu * mu;
  float inv = rsqrtf(var + 1e-5f);
  const float4* g4 = (const float4*)gamma;
  const float4* b4 = (const float4*)beta;
  bf16_t* xo = xn + (long)tok * DM;
#pragma unroll
  for (int i = 0; i < 3; i++) {
    float4 v = (i == 0) ? v0 : (i == 1) ? v1 : v2;
    float4 g = g4[lane + 64 * i], b = b4[lane + 64 * i];
    bf16x4 o;
    o[0] = (bf16_t)((v.x - mu) * inv * g.x + b.x);
    o[1] = (bf16_t)((v.y - mu) * inv * g.y + b.y);
    o[2] = (bf16_t)((v.z - mu) * inv * g.z + b.z);
    o[3] = (bf16_t)((v.w - mu) * inv * g.w + b.w);
    *(bf16x4*)(xo + lane * 4 + i * 256) = o;
  }
}

// ---------------- depthwise causal conv (4 taps) + hs (token per wave) -------
__global__ __launch_bounds__(256)
void conv_kernel(const bf16_t* __restrict__ xz, const float* __restrict__ conv_w,
                 const float* __restrict__ a_vec, const float* __restrict__ b_vec,
                 bf16_t* __restrict__ x1, float* __restrict__ hs) {
  const int tok = blockIdx.x * 4 + (threadIdx.x >> 6);
  const int lane = threadIdx.x & 63;
  const int l = tok & (SEQ_LEN - 1);
  const bf16_t* base = xz + (long)tok * 1536;
  const float4* w4 = (const float4*)conv_w;
  float s = 0.f, sa = 0.f, sb = 0.f;

  {
    const int c0 = lane * 8;
    bf16x8 cur = *(const bf16x8*)(base + c0);
    bf16x8 p1 = {}, p2 = {}, p3 = {};
    if (l >= 1) p1 = *(const bf16x8*)(base + c0 - 1536);
    if (l >= 2) p2 = *(const bf16x8*)(base + c0 - 2 * 1536);
    if (l >= 3) p3 = *(const bf16x8*)(base + c0 - 3 * 1536);
    bf16x8 o;
#pragma unroll
    for (int j = 0; j < 8; j++) {
      float4 w = w4[c0 + j];
      float acc = w.w * (float)cur[j] + w.z * (float)p1[j] +
                  w.y * (float)p2[j] + w.x * (float)p3[j];
      bf16_t xb = (bf16_t)acc;
      o[j] = xb;
      float xv = (float)xb;
      s += xv; sa += xv * a_vec[c0 + j]; sb += xv * b_vec[c0 + j];
    }
    *(bf16x8*)(x1 + (long)tok * DM + c0) = o;
  }
  {
    const int c0 = 512 + lane * 4;
    bf16x4 cur = *(const bf16x4*)(base + c0);
    bf16x4 p1 = {}, p2 = {}, p3 = {};
    if (l >= 1) p1 = *(const bf16x4*)(base + c0 - 1536);
    if (l >= 2) p2 = *(const bf16x4*)(base + c0 - 2 * 1536);
    if (l >= 3) p3 = *(const bf16x4*)(base + c0 - 3 * 1536);
    bf16x4 o;
#pragma unroll
    for (int j = 0; j < 4; j++) {
      float4 w = w4[c0 + j];
      float acc = w.w * (float)cur[j] + w.z * (float)p1[j] +
                  w.y * (float)p2[j] + w.x * (float)p3[j];
      bf16_t xb = (bf16_t)acc;
      o[j] = xb;
      float xv = (float)xb;
      s += xv; sa += xv * a_vec[c0 + j]; sb += xv * b_vec[c0 + j];
    }
    *(bf16x4*)(x1 + (long)tok * DM + c0) = o;
  }
  for (int o = 1; o < 64; o <<= 1) {
    s += __shfl_xor(s, o); sa += __shfl_xor(sa, o); sb += __shfl_xor(sb, o);
  }
  if (lane == 0) hs[tok] = sa + s * sb;
}

// ========= 256x256 8-phase MFMA GEMM, COUNTED vmcnt (T2+T3+T4+T5) =========
// C[M,N] = A[M,K] @ BT[N,K]^T. 512 thr / 8 waves (2M x 4N), wave-tile 128x64,
// acc 8x4 of 16x16x32. BK=64, 2 K-tiles per iteration, 8 phases.
// Stage placement (per wave, 4 loads each):
//   P1: B(2it+1)->buf1   P4: A(2it+2)->buf0 (buf0 dead after P3's last read)
//   P5: B(2it+2)->buf0   P8: A(2it+3)->buf1 (buf1 dead after P7's last read)
// Gates: end-P4 and end-P8 use vmcnt(4) (the 4 newest A-loads stay in flight;
// the tile needed next was staged 3-4 phases earlier). Tail iters -> vmcnt(0).
// Each wave drains ITS OWN loads pre-barrier; the barrier publishes all waves'
// LDS writes. ds_reads issue BEFORE the phase barrier (latency overlaps it).
// LDS swizzle (verified R5: bank conflicts 9.4M -> 0): 16B slot
// s_phys = s_log ^ (row&7); linear gload_lds dest + pre-swizzled global src.
template <int OUT_MODE>
__global__ __launch_bounds__(512, 2)
void gemm256_kernel(const bf16_t* __restrict__ A, const bf16_t* __restrict__ BT,
                    void* __restrict__ outp, const float* __restrict__ res,
                    const bf16_t* __restrict__ x1, const bf16_t* __restrict__ xz,
                    const float* __restrict__ hs, const float* __restrict__ Dp,
                    int M, int N, int K) {
  __shared__ __align__(16) bf16_t As[2][256 * 64];  // 64 KB
  __shared__ __align__(16) bf16_t Bs[2][256 * 64];  // 64 KB

  const int nby = N >> 8;                     // N/256
  const int nwg = (M >> 8) * nby;
  const int cpx = nwg >> 3;
  const int wg = blockIdx.x;
  const int swz = (wg & 7) * cpx + (wg >> 3); // bijective (nwg % 8 == 0)
  const int bx = swz / nby;
  const int by = swz - bx * nby;
  const int m0 = bx << 8;
  const int n0 = by << 8;

  const int t = threadIdx.x;
  const int lane = t & 63;
  const int wave = t >> 6;                    // 0..7
  const int wm = (wave >> 2) * 128;           // 0 or 128
  const int wn = (wave & 3) * 64;             // 0,64,128,192
  const int l15 = lane & 15;
  const int quad = lane >> 4;

  // swizzled k-slot offsets for ds_read (elements)
  const int sx0 = (((0 * 4) + quad) ^ (lane & 7)) * 8;
  const int sx1 = (((1 * 4) + quad) ^ (lane & 7)) * 8;

  // staging: lane covers row (chunkbase + lane>>3), pre-swizzled global k-slot
  const int srow = lane >> 3;
  const int scol = (((lane & 7) ^ ((lane >> 3) & 7))) * 8;

  f32x4 acc[8][4] = {};
  bf16x8 a[4][2], b0[2][2], b1[2][2];

  const bf16_t* Abase = A + (long)m0 * K + scol;
  const bf16_t* Bbase = BT + (long)n0 * K + scol;

#define STAGE_A(buf, kt) do {                                               \
    const long kk_ = (long)(kt) * 64;                                       \
    _Pragma("unroll")                                                       \
    for (int h_ = 0; h_ < 2; h_++) {                                        \
      _Pragma("unroll")                                                     \
      for (int j_ = 0; j_ < 2; j_++) {                                      \
        const int rowl_ = h_ * 128 + wave * 16 + j_ * 8;                    \
        load16_to_lds(Abase + (long)(rowl_ + srow) * K + kk_,               \
                      &As[buf][rowl_ * 64]);                                \
      } } } while (0)

#define STAGE_B(buf, kt) do {                                               \
    const long kk_ = (long)(kt) * 64;                                       \
    _Pragma("unroll")                                                       \
    for (int h_ = 0; h_ < 2; h_++) {                                        \
      _Pragma("unroll")                                                     \
      for (int j_ = 0; j_ < 2; j_++) {                                      \
        const int rowl_ = h_ * 128 + wave * 16 + j_ * 8;                    \
        load16_to_lds(Bbase + (long)(rowl_ + srow) * K + kk_,               \
                      &Bs[buf][rowl_ * 64]);                                \
      } } } while (0)

#define READ_A(qm, buf) do {                                                \
    _Pragma("unroll")                                                       \
    for (int mi_ = 0; mi_ < 4; mi_++) {                                     \
      const bf16_t* p_ = &As[buf][(wm + (qm) * 64 + mi_ * 16 + l15) * 64];  \
      a[mi_][0] = *(const bf16x8*)(p_ + sx0);                               \
      a[mi_][1] = *(const bf16x8*)(p_ + sx1);                               \
    } } while (0)

#define READ_B(dst, qn, buf) do {                                           \
    _Pragma("unroll")                                                       \
    for (int ni_ = 0; ni_ < 2; ni_++) {                                     \
      const bf16_t* p_ = &Bs[buf][(wn + (qn) * 32 + ni_ * 16 + l15) * 64];  \
      dst[ni_][0] = *(const bf16x8*)(p_ + sx0);                             \
      dst[ni_][1] = *(const bf16x8*)(p_ + sx1);                             \
    } } while (0)

#define MFMA16(qm, qn, breg) do {                                           \
    __builtin_amdgcn_s_setprio(1);                                          \
    _Pragma("unroll")                                                       \
    for (int mi_ = 0; mi_ < 4; mi_++) {                                     \
      _Pragma("unroll")                                                     \
      for (int ni_ = 0; ni_ < 2; ni_++) {                                   \
        acc[(qm) * 4 + mi_][(qn) * 2 + ni_] =                               \
            __builtin_amdgcn_mfma_f32_16x16x32_bf16(                        \
                a[mi_][0], breg[ni_][0],                                    \
                acc[(qm) * 4 + mi_][(qn) * 2 + ni_], 0, 0, 0);              \
        acc[(qm) * 4 + mi_][(qn) * 2 + ni_] =                               \
            __builtin_amdgcn_mfma_f32_16x16x32_bf16(                        \
                a[mi_][1], breg[ni_][1],                                    \
                acc[(qm) * 4 + mi_][(qn) * 2 + ni_], 0, 0, 0);              \
      } }                                                                   \
    __builtin_amdgcn_s_setprio(0);                                          \
  } while (0)

#define BAR() do { asm volatile("" ::: "memory");                           \
    __builtin_amdgcn_s_barrier();                                           \
    asm volatile("" ::: "memory"); } while (0)

  const int NT = K >> 6;   // K/64 K-tiles (12 for K=768)
  const int NI = NT >> 1;  // iterations, 2 K-tiles each

  // prologue: tile0 -> buf0 (A+B), tile1 A -> buf1; counted gate
  STAGE_A(0, 0);
  STAGE_B(0, 0);
  STAGE_A(1, 1);
  asm volatile("s_waitcnt vmcnt(4)" ::: "memory");  // tile0's 8 landed
  BAR();

  for (int it = 0; it < NI; ++it) {
    const int t1k = 2 * it + 1;
    const int t2k = 2 * it + 2;
    const int t3k = 2 * it + 3;
    // ---- P1: stage B(t1k)->buf1 ; reads Q0 of buf0 ; MFMA(0,0) ----
    STAGE_B(1, t1k);
    READ_A(0, 0);
    READ_B(b0, 0, 0);
    BAR();
    MFMA16(0, 0, b0);
    // ---- P2 ----
    READ_B(b1, 1, 0);
    BAR();
    MFMA16(0, 1, b1);
    // ---- P3 (last buf0 reads) ----
    READ_A(1, 0);
    BAR();
    MFMA16(1, 1, b1);
    // ---- P4: buf0 dead -> stage A(t2k); counted gate for buf1 ----
    if (t2k < NT) STAGE_A(0, t2k);
    MFMA16(1, 0, b0);
    if (t2k < NT) { asm volatile("s_waitcnt vmcnt(4)" ::: "memory"); }
    else          { asm volatile("s_waitcnt vmcnt(0)" ::: "memory"); }
    BAR();                       // buf1 (tile t1k) published
    // ---- P5: stage B(t2k)->buf0 ; reads Q0 of buf1 ; MFMA(0,0) ----
    if (t2k < NT) STAGE_B(0, t2k);
    READ_A(0, 1);
    READ_B(b0, 0, 1);
    BAR();
    MFMA16(0, 0, b0);
    // ---- P6 ----
    READ_B(b1, 1, 1);
    BAR();
    MFMA16(0, 1, b1);
    // ---- P7 (last buf1 reads) ----
    READ_A(1, 1);
    BAR();
    MFMA16(1, 1, b1);
    // ---- P8: buf1 dead -> stage A(t3k); counted gate for buf0 ----
    if (t3k < NT) STAGE_A(1, t3k);
    MFMA16(1, 0, b0);
    if (t3k < NT) { asm volatile("s_waitcnt vmcnt(4)" ::: "memory"); }
    else          { asm volatile("s_waitcnt vmcnt(0)" ::: "memory"); }
    BAR();                       // buf0 (tile t2k) published
  }

  // -------- epilogue --------
#pragma unroll
  for (int mi = 0; mi < 8; mi++) {
#pragma unroll
    for (int r = 0; r < 4; r++) {
      const int row = m0 + wm + mi * 16 + quad * 4 + r;
      float hsv = 0.f;
      if (OUT_MODE == 1) hsv = hs[row];
#pragma unroll
      for (int ni = 0; ni < 4; ni++) {
        const int col = n0 + wn + ni * 16 + l15;
        const long o = (long)row * N + col;
        float v = acc[mi][ni][r];
        if (OUT_MODE == 0) {
          ((bf16_t*)outp)[o] = (bf16_t)v;
        } else if (OUT_MODE == 1) {
          float xv = (float)x1[(long)row * DM + col];
          float zv = (float)xz[(long)row * 1536 + DM + col];
          float yv = v * hsv + Dp[col] * xv;
          yv *= zv / (1.f + __expf(-zv));
          ((bf16_t*)outp)[o] = (bf16_t)yv;
        } else {
          ((float*)outp)[o] = v + res[o];
        }
      }
    }
  }
#undef STAGE_A
#undef STAGE_B
#undef READ_A
#undef READ_B
#undef MFMA16
#undef BAR
}

// ---------------- launch ----------------
extern "C" void kernel_launch(void* const* d_in, const int* in_sizes, int n_in,
                              void* d_out, int out_size, void* d_ws, size_t ws_size,
                              hipStream_t stream) {
  const float* x      = (const float*)d_in[0];
  const float* W_in   = (const float*)d_in[1];
  const float* conv_w = (const float*)d_in[2];
  const float* W_x    = (const float*)d_in[3];
  const float* A_log  = (const float*)d_in[4];
  const float* Dp     = (const float*)d_in[5];
  const float* W_out  = (const float*)d_in[6];
  const float* gamma  = (const float*)d_in[7];
  const float* beta   = (const float*)d_in[8];
  float* out = (float*)d_out;

  char* ws = (char*)d_ws;
  bf16_t* w_in_T  = (bf16_t*)(ws + 0);          // 1536x768 bf16
  bf16_t* w_c_T   = (bf16_t*)(ws + 2359296);    //  768x768 bf16
  bf16_t* w_out_T = (bf16_t*)(ws + 3538944);    //  768x768 bf16
  float*  a_vec   = (float*)(ws + 4718592);
  float*  b_vec   = (float*)(ws + 4721664);
  float*  hs      = (float*)(ws + 4724736);     // 32768 f32
  bf16_t* xn      = (bf16_t*)(ws + 4855808);    // 32768x768 bf16 (reused as y)
  bf16_t* xz      = (bf16_t*)(ws + 55187456);   // 32768x1536 bf16
  bf16_t* x1      = (bf16_t*)(ws + 155850752);  // 32768x768 bf16
  bf16_t* y       = xn;

  cast_transpose_kernel<<<dim3(1536 * 768 / 256), 256, 0, stream>>>(W_in, w_in_T, 768, 1536, 1536, 0);
  cast_transpose_kernel<<<dim3(768 * 768 / 256), 256, 0, stream>>>(W_x, w_c_T, 768, 768, 784, 16);
  cast_transpose_kernel<<<dim3(768 * 768 / 256), 256, 0, stream>>>(W_out, w_out_T, 768, 768, 768, 0);
  ab_kernel<<<dim3(3), 256, 0, stream>>>(W_x, A_log, a_vec, b_vec);

  ln_kernel<<<dim3(TOKENS / 4), 256, 0, stream>>>(x, gamma, beta, xn);

  gemm256_kernel<0><<<dim3((TOKENS / 256) * (1536 / 256)), 512, 0, stream>>>(
      xn, w_in_T, (void*)xz, nullptr, nullptr, nullptr, nullptr, nullptr,
      TOKENS, 1536, 768);

  conv_kernel<<<dim3(TOKENS / 4), 256, 0, stream>>>(xz, conv_w, a_vec, b_vec, x1, hs);

  gemm256_kernel<1><<<dim3((TOKENS / 256) * (768 / 256)), 512, 0, stream>>>(
      x1, w_c_T, (void*)y, nullptr, x1, xz, hs, Dp,
      TOKENS, 768, 768);

  gemm256_kernel<2><<<dim3((TOKENS / 256) * (768 / 256)), 512, 0, stream>>>(
      y, w_out_T, (void*)out, x, nullptr, nullptr, nullptr, nullptr,
      TOKENS, 768, 768);
}

// Round 7
// 476.122 us; speedup vs baseline: 1.1139x; 1.0740x over previous
//
#include <hip/hip_runtime.h>

typedef __bf16 bf16_t;
typedef __bf16 bf16x8 __attribute__((ext_vector_type(8)));
typedef __bf16 bf16x4 __attribute__((ext_vector_type(4)));
typedef float f32x4 __attribute__((ext_vector_type(4)));

#define DM 768
#define SEQ_LEN 4096
#define TOKENS 32768

// async 16B global -> LDS (wave-uniform LDS base + lane*16)
__device__ __forceinline__ void load16_to_lds(const void* g, void* l) {
  __builtin_amdgcn_global_load_lds(
      (const __attribute__((address_space(1))) unsigned int*)g,
      (__attribute__((address_space(3))) unsigned int*)l, 16, 0, 0);
}

// ============ fused prep: 3 weight transposes + ab + layernorm ============
// block ranges: [0,4608) W_in^T ; [4608,6912) w_c^T ; [6912,9216) w_out^T ;
// [9216,9219) ab ; [9219,17411) layernorm. All segments independent.
__global__ __launch_bounds__(256)
void prep_kernel(const float* __restrict__ W_in, const float* __restrict__ W_x,
                 const float* __restrict__ W_out, const float* __restrict__ A_log,
                 const float* __restrict__ x, const float* __restrict__ gamma,
                 const float* __restrict__ beta,
                 bf16_t* __restrict__ w_in_T, bf16_t* __restrict__ w_c_T,
                 bf16_t* __restrict__ w_out_T, float* __restrict__ a_vec,
                 float* __restrict__ b_vec, bf16_t* __restrict__ xn) {
  const int bid = blockIdx.x;
  if (bid < 4608) {                       // w_in_T[n*768+k] = W_in[k*1536+n]
    int idx = bid * 256 + threadIdx.x;
    int n = idx / 768, k = idx - n * 768;
    w_in_T[idx] = (bf16_t)W_in[k * 1536 + n];
  } else if (bid < 6912) {                // w_c_T[n*768+k] = W_x[k*784+16+n]
    int idx = (bid - 4608) * 256 + threadIdx.x;
    int n = idx / 768, k = idx - n * 768;
    w_c_T[idx] = (bf16_t)W_x[k * 784 + 16 + n];
  } else if (bid < 9216) {                // w_out_T[n*768+k] = W_out[k*768+n]
    int idx = (bid - 6912) * 256 + threadIdx.x;
    int n = idx / 768, k = idx - n * 768;
    w_out_T[idx] = (bf16_t)W_out[k * 768 + n];
  } else if (bid < 9219) {                // ab
    int k = (bid - 9216) * 256 + threadIdx.x;
    if (k < DM) {
      float a = 0.f, b = 0.f;
#pragma unroll
      for (int d = 0; d < 16; d++) {
        a -= __expf(A_log[k * 16 + d]);
        b += W_x[(long)k * 784 + d];
      }
      a_vec[k] = a;
      b_vec[k] = b;
    }
  } else {                                // layernorm (token per wave)
    const int tok = (bid - 9219) * 4 + (threadIdx.x >> 6);
    const int lane = threadIdx.x & 63;
    const float4* xr = (const float4*)(x + (long)tok * DM);
    float4 v0 = xr[lane], v1 = xr[lane + 64], v2 = xr[lane + 128];
    float s = v0.x + v0.y + v0.z + v0.w + v1.x + v1.y + v1.z + v1.w +
              v2.x + v2.y + v2.z + v2.w;
    float ss = v0.x * v0.x + v0.y * v0.y + v0.z * v0.z + v0.w * v0.w +
               v1.x * v1.x + v1.y * v1.y + v1.z * v1.z + v1.w * v1.w +
               v2.x * v2.x + v2.y * v2.y + v2.z * v2.z + v2.w * v2.w;
    for (int o = 1; o < 64; o <<= 1) { s += __shfl_xor(s, o); ss += __shfl_xor(ss, o); }
    float mu = s * (1.0f / DM);
    float var = ss * (1.0f / DM) - mu * mu;
    float inv = rsqrtf(var + 1e-5f);
    const float4* g4 = (const float4*)gamma;
    const float4* b4 = (const float4*)beta;
    bf16_t* xo = xn + (long)tok * DM;
#pragma unroll
    for (int i = 0; i < 3; i++) {
      float4 v = (i == 0) ? v0 : (i == 1) ? v1 : v2;
      float4 g = g4[lane + 64 * i], b = b4[lane + 64 * i];
      bf16x4 o;
      o[0] = (bf16_t)((v.x - mu) * inv * g.x + b.x);
      o[1] = (bf16_t)((v.y - mu) * inv * g.y + b.y);
      o[2] = (bf16_t)((v.z - mu) * inv * g.z + b.z);
      o[3] = (bf16_t)((v.w - mu) * inv * g.w + b.w);
      *(bf16x4*)(xo + lane * 4 + i * 256) = o;
    }
  }
}

// ---------------- depthwise causal conv (4 taps) + hs (token per wave) -------
__global__ __launch_bounds__(256)
void conv_kernel(const bf16_t* __restrict__ xz, const float* __restrict__ conv_w,
                 const float* __restrict__ a_vec, const float* __restrict__ b_vec,
                 bf16_t* __restrict__ x1, float* __restrict__ hs) {
  const int tok = blockIdx.x * 4 + (threadIdx.x >> 6);
  const int lane = threadIdx.x & 63;
  const int l = tok & (SEQ_LEN - 1);
  const bf16_t* base = xz + (long)tok * 1536;
  const float4* w4 = (const float4*)conv_w;
  float s = 0.f, sa = 0.f, sb = 0.f;

  {
    const int c0 = lane * 8;
    bf16x8 cur = *(const bf16x8*)(base + c0);
    bf16x8 p1 = {}, p2 = {}, p3 = {};
    if (l >= 1) p1 = *(const bf16x8*)(base + c0 - 1536);
    if (l >= 2) p2 = *(const bf16x8*)(base + c0 - 2 * 1536);
    if (l >= 3) p3 = *(const bf16x8*)(base + c0 - 3 * 1536);
    bf16x8 o;
#pragma unroll
    for (int j = 0; j < 8; j++) {
      float4 w = w4[c0 + j];
      float acc = w.w * (float)cur[j] + w.z * (float)p1[j] +
                  w.y * (float)p2[j] + w.x * (float)p3[j];
      bf16_t xb = (bf16_t)acc;
      o[j] = xb;
      float xv = (float)xb;
      s += xv; sa += xv * a_vec[c0 + j]; sb += xv * b_vec[c0 + j];
    }
    *(bf16x8*)(x1 + (long)tok * DM + c0) = o;
  }
  {
    const int c0 = 512 + lane * 4;
    bf16x4 cur = *(const bf16x4*)(base + c0);
    bf16x4 p1 = {}, p2 = {}, p3 = {};
    if (l >= 1) p1 = *(const bf16x4*)(base + c0 - 1536);
    if (l >= 2) p2 = *(const bf16x4*)(base + c0 - 2 * 1536);
    if (l >= 3) p3 = *(const bf16x4*)(base + c0 - 3 * 1536);
    bf16x4 o;
#pragma unroll
    for (int j = 0; j < 4; j++) {
      float4 w = w4[c0 + j];
      float acc = w.w * (float)cur[j] + w.z * (float)p1[j] +
                  w.y * (float)p2[j] + w.x * (float)p3[j];
      bf16_t xb = (bf16_t)acc;
      o[j] = xb;
      float xv = (float)xb;
      s += xv; sa += xv * a_vec[c0 + j]; sb += xv * b_vec[c0 + j];
    }
    *(bf16x4*)(x1 + (long)tok * DM + c0) = o;
  }
  for (int o = 1; o < 64; o <<= 1) {
    s += __shfl_xor(s, o); sa += __shfl_xor(sa, o); sb += __shfl_xor(sb, o);
  }
  if (lane == 0) hs[tok] = sa + s * sb;
}

// ========= 256x256 8-phase MFMA GEMM, COUNTED vmcnt (GEMM1 only) =========
// Measured R6: < 95 us for GEMM1 (vs 111 at 128^2); bank conflicts 0.
// Grid 768 blocks = 3.0 exact residency rounds at 1 block/CU.
template <int OUT_MODE>
__global__ __launch_bounds__(512, 2)
void gemm256_kernel(const bf16_t* __restrict__ A, const bf16_t* __restrict__ BT,
                    void* __restrict__ outp, const float* __restrict__ res,
                    const bf16_t* __restrict__ x1, const bf16_t* __restrict__ xz,
                    const float* __restrict__ hs, const float* __restrict__ Dp,
                    int M, int N, int K) {
  __shared__ __align__(16) bf16_t As[2][256 * 64];  // 64 KB
  __shared__ __align__(16) bf16_t Bs[2][256 * 64];  // 64 KB

  const int nby = N >> 8;
  const int nwg = (M >> 8) * nby;
  const int cpx = nwg >> 3;
  const int wg = blockIdx.x;
  const int swz = (wg & 7) * cpx + (wg >> 3);
  const int bx = swz / nby;
  const int by = swz - bx * nby;
  const int m0 = bx << 8;
  const int n0 = by << 8;

  const int t = threadIdx.x;
  const int lane = t & 63;
  const int wave = t >> 6;
  const int wm = (wave >> 2) * 128;
  const int wn = (wave & 3) * 64;
  const int l15 = lane & 15;
  const int quad = lane >> 4;

  const int sx0 = (((0 * 4) + quad) ^ (lane & 7)) * 8;
  const int sx1 = (((1 * 4) + quad) ^ (lane & 7)) * 8;

  const int srow = lane >> 3;
  const int scol = (((lane & 7) ^ ((lane >> 3) & 7))) * 8;

  f32x4 acc[8][4] = {};
  bf16x8 a[4][2], b0[2][2], b1[2][2];

  const bf16_t* Abase = A + (long)m0 * K + scol;
  const bf16_t* Bbase = BT + (long)n0 * K + scol;

#define STAGE_A(buf, kt) do {                                               \
    const long kk_ = (long)(kt) * 64;                                       \
    _Pragma("unroll")                                                       \
    for (int h_ = 0; h_ < 2; h_++) {                                        \
      _Pragma("unroll")                                                     \
      for (int j_ = 0; j_ < 2; j_++) {                                      \
        const int rowl_ = h_ * 128 + wave * 16 + j_ * 8;                    \
        load16_to_lds(Abase + (long)(rowl_ + srow) * K + kk_,               \
                      &As[buf][rowl_ * 64]);                                \
      } } } while (0)

#define STAGE_B(buf, kt) do {                                               \
    const long kk_ = (long)(kt) * 64;                                       \
    _Pragma("unroll")                                                       \
    for (int h_ = 0; h_ < 2; h_++) {                                        \
      _Pragma("unroll")                                                     \
      for (int j_ = 0; j_ < 2; j_++) {                                      \
        const int rowl_ = h_ * 128 + wave * 16 + j_ * 8;                    \
        load16_to_lds(Bbase + (long)(rowl_ + srow) * K + kk_,               \
                      &Bs[buf][rowl_ * 64]);                                \
      } } } while (0)

#define READ_A(qm, buf) do {                                                \
    _Pragma("unroll")                                                       \
    for (int mi_ = 0; mi_ < 4; mi_++) {                                     \
      const bf16_t* p_ = &As[buf][(wm + (qm) * 64 + mi_ * 16 + l15) * 64];  \
      a[mi_][0] = *(const bf16x8*)(p_ + sx0);                               \
      a[mi_][1] = *(const bf16x8*)(p_ + sx1);                               \
    } } while (0)

#define READ_B(dst, qn, buf) do {                                           \
    _Pragma("unroll")                                                       \
    for (int ni_ = 0; ni_ < 2; ni_++) {                                     \
      const bf16_t* p_ = &Bs[buf][(wn + (qn) * 32 + ni_ * 16 + l15) * 64];  \
      dst[ni_][0] = *(const bf16x8*)(p_ + sx0);                             \
      dst[ni_][1] = *(const bf16x8*)(p_ + sx1);                             \
    } } while (0)

#define MFMA16(qm, qn, breg) do {                                           \
    __builtin_amdgcn_s_setprio(1);                                          \
    _Pragma("unroll")                                                       \
    for (int mi_ = 0; mi_ < 4; mi_++) {                                     \
      _Pragma("unroll")                                                     \
      for (int ni_ = 0; ni_ < 2; ni_++) {                                   \
        acc[(qm) * 4 + mi_][(qn) * 2 + ni_] =                               \
            __builtin_amdgcn_mfma_f32_16x16x32_bf16(                        \
                a[mi_][0], breg[ni_][0],                                    \
                acc[(qm) * 4 + mi_][(qn) * 2 + ni_], 0, 0, 0);              \
        acc[(qm) * 4 + mi_][(qn) * 2 + ni_] =                               \
            __builtin_amdgcn_mfma_f32_16x16x32_bf16(                        \
                a[mi_][1], breg[ni_][1],                                    \
                acc[(qm) * 4 + mi_][(qn) * 2 + ni_], 0, 0, 0);              \
      } }                                                                   \
    __builtin_amdgcn_s_setprio(0);                                          \
  } while (0)

#define BAR() do { asm volatile("" ::: "memory");                           \
    __builtin_amdgcn_s_barrier();                                           \
    asm volatile("" ::: "memory"); } while (0)

  const int NT = K >> 6;
  const int NI = NT >> 1;

  STAGE_A(0, 0);
  STAGE_B(0, 0);
  STAGE_A(1, 1);
  asm volatile("s_waitcnt vmcnt(4)" ::: "memory");
  BAR();

  for (int it = 0; it < NI; ++it) {
    const int t1k = 2 * it + 1;
    const int t2k = 2 * it + 2;
    const int t3k = 2 * it + 3;
    STAGE_B(1, t1k);            // P1
    READ_A(0, 0);
    READ_B(b0, 0, 0);
    BAR();
    MFMA16(0, 0, b0);
    READ_B(b1, 1, 0);           // P2
    BAR();
    MFMA16(0, 1, b1);
    READ_A(1, 0);               // P3
    BAR();
    MFMA16(1, 1, b1);
    if (t2k < NT) STAGE_A(0, t2k);  // P4
    MFMA16(1, 0, b0);
    if (t2k < NT) { asm volatile("s_waitcnt vmcnt(4)" ::: "memory"); }
    else          { asm volatile("s_waitcnt vmcnt(0)" ::: "memory"); }
    BAR();
    if (t2k < NT) STAGE_B(0, t2k);  // P5
    READ_A(0, 1);
    READ_B(b0, 0, 1);
    BAR();
    MFMA16(0, 0, b0);
    READ_B(b1, 1, 1);           // P6
    BAR();
    MFMA16(0, 1, b1);
    READ_A(1, 1);               // P7
    BAR();
    MFMA16(1, 1, b1);
    if (t3k < NT) STAGE_A(1, t3k);  // P8
    MFMA16(1, 0, b0);
    if (t3k < NT) { asm volatile("s_waitcnt vmcnt(4)" ::: "memory"); }
    else          { asm volatile("s_waitcnt vmcnt(0)" ::: "memory"); }
    BAR();
  }

#pragma unroll
  for (int mi = 0; mi < 8; mi++) {
#pragma unroll
    for (int r = 0; r < 4; r++) {
      const int row = m0 + wm + mi * 16 + quad * 4 + r;
      float hsv = 0.f;
      if (OUT_MODE == 1) hsv = hs[row];
#pragma unroll
      for (int ni = 0; ni < 4; ni++) {
        const int col = n0 + wn + ni * 16 + l15;
        const long o = (long)row * N + col;
        float v = acc[mi][ni][r];
        if (OUT_MODE == 0) {
          ((bf16_t*)outp)[o] = (bf16_t)v;
        } else if (OUT_MODE == 1) {
          float xv = (float)x1[(long)row * DM + col];
          float zv = (float)xz[(long)row * 1536 + DM + col];
          float yv = v * hsv + Dp[col] * xv;
          yv *= zv / (1.f + __expf(-zv));
          ((bf16_t*)outp)[o] = (bf16_t)yv;
        } else {
          ((float*)outp)[o] = v + res[o];
        }
      }
    }
  }
#undef STAGE_A
#undef STAGE_B
#undef READ_A
#undef READ_B
#undef MFMA16
#undef BAR
}

// ---------------- 128x128 MFMA GEMM (R2-verified; GEMM2/GEMM3) ----------
// 4 waves, wave-tile 64x64, acc 4x4; grid 1536 blocks @ 3/CU = 2.0 rounds.
template <int OUT_MODE>
__global__ __launch_bounds__(256, 3)
void gemm128_kernel(const bf16_t* __restrict__ A, const bf16_t* __restrict__ BT,
                    void* __restrict__ outp, const float* __restrict__ res,
                    const bf16_t* __restrict__ x1, const bf16_t* __restrict__ xz,
                    const float* __restrict__ hs, const float* __restrict__ Dp,
                    int M, int N, int K) {
  __shared__ __align__(16) bf16_t As[128 * 32];  // 8 KB
  __shared__ __align__(16) bf16_t Bs[128 * 32];  // 8 KB

  const int nby = N >> 7;
  const int nwg = (M >> 7) * nby;
  const int cpx = nwg >> 3;
  const int wg = blockIdx.x;
  const int swz = (wg & 7) * cpx + (wg >> 3);
  const int bx = swz / nby;
  const int by = swz - bx * nby;
  const int m0 = bx << 7;
  const int n0 = by << 7;

  const int t = threadIdx.x;
  const int lane = t & 63;
  const int wave = t >> 6;
  const int wm = (wave >> 1) * 64;
  const int wn = (wave & 1) * 64;
  const int l15 = lane & 15;
  const int quad = lane >> 4;

  f32x4 acc[4][4] = {};

  const int sr = lane >> 2;
  const int sc = (lane & 3) * 8;
  const bf16_t* Ag[2];
  bf16_t* lA[2];
#pragma unroll
  for (int i = 0; i < 2; i++) {
    int ch = wave * 2 + i;
    Ag[i] = A + (long)(m0 + ch * 16 + sr) * K + sc;
    lA[i] = As + ch * 512 + lane * 8;
  }
  const bf16_t* Bg[2];
  bf16_t* lB[2];
#pragma unroll
  for (int i = 0; i < 2; i++) {
    int ch = wave * 2 + i;
    Bg[i] = BT + (long)(n0 + ch * 16 + sr) * K + sc;
    lB[i] = Bs + ch * 512 + lane * 8;
  }

  for (int k0 = 0; k0 < K; k0 += 32) {
#pragma unroll
    for (int i = 0; i < 2; i++) load16_to_lds(Ag[i] + k0, lA[i]);
#pragma unroll
    for (int i = 0; i < 2; i++) load16_to_lds(Bg[i] + k0, lB[i]);
    __syncthreads();
    bf16x8 bfrag[4];
#pragma unroll
    for (int ni = 0; ni < 4; ni++)
      bfrag[ni] = *(const bf16x8*)&Bs[(wn + ni * 16 + l15) * 32 + quad * 8];
#pragma unroll
    for (int mi = 0; mi < 4; mi++) {
      bf16x8 afrag = *(const bf16x8*)&As[(wm + mi * 16 + l15) * 32 + quad * 8];
#pragma unroll
      for (int ni = 0; ni < 4; ni++)
        acc[mi][ni] = __builtin_amdgcn_mfma_f32_16x16x32_bf16(afrag, bfrag[ni], acc[mi][ni], 0, 0, 0);
    }
    __syncthreads();
  }

#pragma unroll
  for (int mi = 0; mi < 4; mi++) {
#pragma unroll
    for (int r = 0; r < 4; r++) {
      const int row = m0 + wm + mi * 16 + quad * 4 + r;
      float hsv = 0.f;
      if (OUT_MODE == 1) hsv = hs[row];
#pragma unroll
      for (int ni = 0; ni < 4; ni++) {
        const int col = n0 + wn + ni * 16 + l15;
        const long o = (long)row * N + col;
        float v = acc[mi][ni][r];
        if (OUT_MODE == 0) {
          ((bf16_t*)outp)[o] = (bf16_t)v;
        } else if (OUT_MODE == 1) {
          float xv = (float)x1[(long)row * DM + col];
          float zv = (float)xz[(long)row * 1536 + DM + col];
          float yv = v * hsv + Dp[col] * xv;
          yv *= zv / (1.f + __expf(-zv));
          ((bf16_t*)outp)[o] = (bf16_t)yv;
        } else {
          ((float*)outp)[o] = v + res[o];
        }
      }
    }
  }
}

// ---------------- launch ----------------
extern "C" void kernel_launch(void* const* d_in, const int* in_sizes, int n_in,
                              void* d_out, int out_size, void* d_ws, size_t ws_size,
                              hipStream_t stream) {
  const float* x      = (const float*)d_in[0];
  const float* W_in   = (const float*)d_in[1];
  const float* conv_w = (const float*)d_in[2];
  const float* W_x    = (const float*)d_in[3];
  const float* A_log  = (const float*)d_in[4];
  const float* Dp     = (const float*)d_in[5];
  const float* W_out  = (const float*)d_in[6];
  const float* gamma  = (const float*)d_in[7];
  const float* beta   = (const float*)d_in[8];
  float* out = (float*)d_out;

  char* ws = (char*)d_ws;
  bf16_t* w_in_T  = (bf16_t*)(ws + 0);          // 1536x768 bf16
  bf16_t* w_c_T   = (bf16_t*)(ws + 2359296);    //  768x768 bf16
  bf16_t* w_out_T = (bf16_t*)(ws + 3538944);    //  768x768 bf16
  float*  a_vec   = (float*)(ws + 4718592);
  float*  b_vec   = (float*)(ws + 4721664);
  float*  hs      = (float*)(ws + 4724736);     // 32768 f32
  bf16_t* xn      = (bf16_t*)(ws + 4855808);    // 32768x768 bf16 (reused as y)
  bf16_t* xz      = (bf16_t*)(ws + 55187456);   // 32768x1536 bf16
  bf16_t* x1      = (bf16_t*)(ws + 155850752);  // 32768x768 bf16
  bf16_t* y       = xn;

  // fused prep: transposes + ab + layernorm (1 launch instead of 5)
  prep_kernel<<<dim3(17411), 256, 0, stream>>>(
      W_in, W_x, W_out, A_log, x, gamma, beta,
      w_in_T, w_c_T, w_out_T, a_vec, b_vec, xn);

  gemm256_kernel<0><<<dim3((TOKENS / 256) * (1536 / 256)), 512, 0, stream>>>(
      xn, w_in_T, (void*)xz, nullptr, nullptr, nullptr, nullptr, nullptr,
      TOKENS, 1536, 768);

  conv_kernel<<<dim3(TOKENS / 4), 256, 0, stream>>>(xz, conv_w, a_vec, b_vec, x1, hs);

  gemm128_kernel<1><<<dim3((TOKENS / 128) * (768 / 128)), 256, 0, stream>>>(
      x1, w_c_T, (void*)y, nullptr, x1, xz, hs, Dp,
      TOKENS, 768, 768);

  gemm128_kernel<2><<<dim3((TOKENS / 128) * (768 / 128)), 256, 0, stream>>>(
      y, w_out_T, (void*)out, x, nullptr, nullptr, nullptr, nullptr,
      TOKENS, 768, 768);
}

// Round 11
// 472.391 us; speedup vs baseline: 1.1227x; 1.0079x over previous
//
#include <hip/hip_runtime.h>

typedef __bf16 bf16_t;
typedef __bf16 bf16x8 __attribute__((ext_vector_type(8)));
typedef __bf16 bf16x4 __attribute__((ext_vector_type(4)));
typedef float f32x4 __attribute__((ext_vector_type(4)));

#define DM 768
#define SEQ_LEN 4096
#define TOKENS 32768

// async 16B global -> LDS (wave-uniform LDS base + lane*16)
__device__ __forceinline__ void load16_to_lds(const void* g, void* l) {
  __builtin_amdgcn_global_load_lds(
      (const __attribute__((address_space(1))) unsigned int*)g,
      (__attribute__((address_space(3))) unsigned int*)l, 16, 0, 0);
}

// ============ fused prep (R7-verified): 3 weight transposes + ab + LN =====
// block ranges: [0,4608) W_in^T ; [4608,6912) w_c^T ; [6912,9216) w_out^T ;
// [9216,9219) ab ; [9219,17411) layernorm. All segments independent.
__global__ __launch_bounds__(256)
void prep_kernel(const float* __restrict__ W_in, const float* __restrict__ W_x,
                 const float* __restrict__ W_out, const float* __restrict__ A_log,
                 const float* __restrict__ x, const float* __restrict__ gamma,
                 const float* __restrict__ beta,
                 bf16_t* __restrict__ w_in_T, bf16_t* __restrict__ w_c_T,
                 bf16_t* __restrict__ w_out_T, float* __restrict__ a_vec,
                 float* __restrict__ b_vec, bf16_t* __restrict__ xn) {
  const int bid = blockIdx.x;
  if (bid < 4608) {                       // w_in_T[n*768+k] = W_in[k*1536+n]
    int idx = bid * 256 + threadIdx.x;
    int n = idx / 768, k = idx - n * 768;
    w_in_T[idx] = (bf16_t)W_in[k * 1536 + n];
  } else if (bid < 6912) {                // w_c_T[n*768+k] = W_x[k*784+16+n]
    int idx = (bid - 4608) * 256 + threadIdx.x;
    int n = idx / 768, k = idx - n * 768;
    w_c_T[idx] = (bf16_t)W_x[k * 784 + 16 + n];
  } else if (bid < 9216) {                // w_out_T[n*768+k] = W_out[k*768+n]
    int idx = (bid - 6912) * 256 + threadIdx.x;
    int n = idx / 768, k = idx - n * 768;
    w_out_T[idx] = (bf16_t)W_out[k * 768 + n];
  } else if (bid < 9219) {                // ab
    int k = (bid - 9216) * 256 + threadIdx.x;
    if (k < DM) {
      float a = 0.f, b = 0.f;
#pragma unroll
      for (int d = 0; d < 16; d++) {
        a -= __expf(A_log[k * 16 + d]);
        b += W_x[(long)k * 784 + d];
      }
      a_vec[k] = a;
      b_vec[k] = b;
    }
  } else {                                // layernorm (token per wave)
    const int tok = (bid - 9219) * 4 + (threadIdx.x >> 6);
    const int lane = threadIdx.x & 63;
    const float4* xr = (const float4*)(x + (long)tok * DM);
    float4 v0 = xr[lane], v1 = xr[lane + 64], v2 = xr[lane + 128];
    float s = v0.x + v0.y + v0.z + v0.w + v1.x + v1.y + v1.z + v1.w +
              v2.x + v2.y + v2.z + v2.w;
    float ss = v0.x * v0.x + v0.y * v0.y + v0.z * v0.z + v0.w * v0.w +
               v1.x * v1.x + v1.y * v1.y + v1.z * v1.z + v1.w * v1.w +
               v2.x * v2.x + v2.y * v2.y + v2.z * v2.z + v2.w * v2.w;
    for (int o = 1; o < 64; o <<= 1) { s += __shfl_xor(s, o); ss += __shfl_xor(ss, o); }
    float mu = s * (1.0f / DM);
    float var = ss * (1.0f / DM) - mu * mu;
    float inv = rsqrtf(var + 1e-5f);
    const float4* g4 = (const float4*)gamma;
    const float4* b4 = (const float4*)beta;
    bf16_t* xo = xn + (long)tok * DM;
#pragma unroll
    for (int i = 0; i < 3; i++) {
      float4 v = (i == 0) ? v0 : (i == 1) ? v1 : v2;
      float4 g = g4[lane + 64 * i], b = b4[lane + 64 * i];
      bf16x4 o;
      o[0] = (bf16_t)((v.x - mu) * inv * g.x + b.x);
      o[1] = (bf16_t)((v.y - mu) * inv * g.y + b.y);
      o[2] = (bf16_t)((v.z - mu) * inv * g.z + b.z);
      o[3] = (bf16_t)((v.w - mu) * inv * g.w + b.w);
      *(bf16x4*)(xo + lane * 4 + i * 256) = o;
    }
  }
}

// ---------------- depthwise causal conv (4 taps) + hs (token per wave) -------
__global__ __launch_bounds__(256)
void conv_kernel(const bf16_t* __restrict__ xz, const float* __restrict__ conv_w,
                 const float* __restrict__ a_vec, const float* __restrict__ b_vec,
                 bf16_t* __restrict__ x1, float* __restrict__ hs) {
  const int tok = blockIdx.x * 4 + (threadIdx.x >> 6);
  const int lane = threadIdx.x & 63;
  const int l = tok & (SEQ_LEN - 1);
  const bf16_t* base = xz + (long)tok * 1536;
  const float4* w4 = (const float4*)conv_w;
  float s = 0.f, sa = 0.f, sb = 0.f;

  {
    const int c0 = lane * 8;
    bf16x8 cur = *(const bf16x8*)(base + c0);
    bf16x8 p1 = {}, p2 = {}, p3 = {};
    if (l >= 1) p1 = *(const bf16x8*)(base + c0 - 1536);
    if (l >= 2) p2 = *(const bf16x8*)(base + c0 - 2 * 1536);
    if (l >= 3) p3 = *(const bf16x8*)(base + c0 - 3 * 1536);
    bf16x8 o;
#pragma unroll
    for (int j = 0; j < 8; j++) {
      float4 w = w4[c0 + j];
      float acc = w.w * (float)cur[j] + w.z * (float)p1[j] +
                  w.y * (float)p2[j] + w.x * (float)p3[j];
      bf16_t xb = (bf16_t)acc;
      o[j] = xb;
      float xv = (float)xb;
      s += xv; sa += xv * a_vec[c0 + j]; sb += xv * b_vec[c0 + j];
    }
    *(bf16x8*)(x1 + (long)tok * DM + c0) = o;
  }
  {
    const int c0 = 512 + lane * 4;
    bf16x4 cur = *(const bf16x4*)(base + c0);
    bf16x4 p1 = {}, p2 = {}, p3 = {};
    if (l >= 1) p1 = *(const bf16x4*)(base + c0 - 1536);
    if (l >= 2) p2 = *(const bf16x4*)(base + c0 - 2 * 1536);
    if (l >= 3) p3 = *(const bf16x4*)(base + c0 - 3 * 1536);
    bf16x4 o;
#pragma unroll
    for (int j = 0; j < 4; j++) {
      float4 w = w4[c0 + j];
      float acc = w.w * (float)cur[j] + w.z * (float)p1[j] +
                  w.y * (float)p2[j] + w.x * (float)p3[j];
      bf16_t xb = (bf16_t)acc;
      o[j] = xb;
      float xv = (float)xb;
      s += xv; sa += xv * a_vec[c0 + j]; sb += xv * b_vec[c0 + j];
    }
    *(bf16x4*)(x1 + (long)tok * DM + c0) = o;
  }
  for (int o = 1; o < 64; o <<= 1) {
    s += __shfl_xor(s, o); sa += __shfl_xor(sa, o); sb += __shfl_xor(sb, o);
  }
  if (lane == 0) hs[tok] = sa + s * sb;
}

// ========= 256x256 8-phase MFMA GEMM, COUNTED vmcnt (GEMM1) =========
// Measured R7: 92 us, MfmaUtil 33.5%, conflicts 0, FETCH ideal.
template <int OUT_MODE>
__global__ __launch_bounds__(512, 2)
void gemm256_kernel(const bf16_t* __restrict__ A, const bf16_t* __restrict__ BT,
                    void* __restrict__ outp, const float* __restrict__ res,
                    const bf16_t* __restrict__ x1, const bf16_t* __restrict__ xz,
                    const float* __restrict__ hs, const float* __restrict__ Dp,
                    int M, int N, int K) {
  __shared__ __align__(16) bf16_t As[2][256 * 64];
  __shared__ __align__(16) bf16_t Bs[2][256 * 64];

  const int nby = N >> 8;
  const int nwg = (M >> 8) * nby;
  const int cpx = nwg >> 3;
  const int wg = blockIdx.x;
  const int swz = (wg & 7) * cpx + (wg >> 3);
  const int bx = swz / nby;
  const int by = swz - bx * nby;
  const int m0 = bx << 8;
  const int n0 = by << 8;

  const int t = threadIdx.x;
  const int lane = t & 63;
  const int wave = t >> 6;
  const int wm = (wave >> 2) * 128;
  const int wn = (wave & 3) * 64;
  const int l15 = lane & 15;
  const int quad = lane >> 4;

  const int sx0 = (((0 * 4) + quad) ^ (lane & 7)) * 8;
  const int sx1 = (((1 * 4) + quad) ^ (lane & 7)) * 8;

  const int srow = lane >> 3;
  const int scol = (((lane & 7) ^ ((lane >> 3) & 7))) * 8;

  f32x4 acc[8][4] = {};
  bf16x8 a[4][2], b0[2][2], b1[2][2];

  const bf16_t* Abase = A + (long)m0 * K + scol;
  const bf16_t* Bbase = BT + (long)n0 * K + scol;

#define STAGE_A(buf, kt) do {                                               \
    const long kk_ = (long)(kt) * 64;                                       \
    _Pragma("unroll")                                                       \
    for (int h_ = 0; h_ < 2; h_++) {                                        \
      _Pragma("unroll")                                                     \
      for (int j_ = 0; j_ < 2; j_++) {                                      \
        const int rowl_ = h_ * 128 + wave * 16 + j_ * 8;                    \
        load16_to_lds(Abase + (long)(rowl_ + srow) * K + kk_,               \
                      &As[buf][rowl_ * 64]);                                \
      } } } while (0)

#define STAGE_B(buf, kt) do {                                               \
    const long kk_ = (long)(kt) * 64;                                       \
    _Pragma("unroll")                                                       \
    for (int h_ = 0; h_ < 2; h_++) {                                        \
      _Pragma("unroll")                                                     \
      for (int j_ = 0; j_ < 2; j_++) {                                      \
        const int rowl_ = h_ * 128 + wave * 16 + j_ * 8;                    \
        load16_to_lds(Bbase + (long)(rowl_ + srow) * K + kk_,               \
                      &Bs[buf][rowl_ * 64]);                                \
      } } } while (0)

#define READ_A(qm, buf) do {                                                \
    _Pragma("unroll")                                                       \
    for (int mi_ = 0; mi_ < 4; mi_++) {                                     \
      const bf16_t* p_ = &As[buf][(wm + (qm) * 64 + mi_ * 16 + l15) * 64];  \
      a[mi_][0] = *(const bf16x8*)(p_ + sx0);                               \
      a[mi_][1] = *(const bf16x8*)(p_ + sx1);                               \
    } } while (0)

#define READ_B(dst, qn, buf) do {                                           \
    _Pragma("unroll")                                                       \
    for (int ni_ = 0; ni_ < 2; ni_++) {                                     \
      const bf16_t* p_ = &Bs[buf][(wn + (qn) * 32 + ni_ * 16 + l15) * 64];  \
      dst[ni_][0] = *(const bf16x8*)(p_ + sx0);                             \
      dst[ni_][1] = *(const bf16x8*)(p_ + sx1);                             \
    } } while (0)

#define MFMA16(qm, qn, breg) do {                                           \
    __builtin_amdgcn_s_setprio(1);                                          \
    _Pragma("unroll")                                                       \
    for (int mi_ = 0; mi_ < 4; mi_++) {                                     \
      _Pragma("unroll")                                                     \
      for (int ni_ = 0; ni_ < 2; ni_++) {                                   \
        acc[(qm) * 4 + mi_][(qn) * 2 + ni_] =                               \
            __builtin_amdgcn_mfma_f32_16x16x32_bf16(                        \
                a[mi_][0], breg[ni_][0],                                    \
                acc[(qm) * 4 + mi_][(qn) * 2 + ni_], 0, 0, 0);              \
        acc[(qm) * 4 + mi_][(qn) * 2 + ni_] =                               \
            __builtin_amdgcn_mfma_f32_16x16x32_bf16(                        \
                a[mi_][1], breg[ni_][1],                                    \
                acc[(qm) * 4 + mi_][(qn) * 2 + ni_], 0, 0, 0);              \
      } }                                                                   \
    __builtin_amdgcn_s_setprio(0);                                          \
  } while (0)

#define BAR() do { asm volatile("" ::: "memory");                           \
    __builtin_amdgcn_s_barrier();                                           \
    asm volatile("" ::: "memory"); } while (0)

  const int NT = K >> 6;
  const int NI = NT >> 1;

  STAGE_A(0, 0);
  STAGE_B(0, 0);
  STAGE_A(1, 1);
  asm volatile("s_waitcnt vmcnt(4)" ::: "memory");
  BAR();

  for (int it = 0; it < NI; ++it) {
    const int t1k = 2 * it + 1;
    const int t2k = 2 * it + 2;
    const int t3k = 2 * it + 3;
    STAGE_B(1, t1k);            // P1
    READ_A(0, 0);
    READ_B(b0, 0, 0);
    BAR();
    MFMA16(0, 0, b0);
    READ_B(b1, 1, 0);           // P2
    BAR();
    MFMA16(0, 1, b1);
    READ_A(1, 0);               // P3
    BAR();
    MFMA16(1, 1, b1);
    if (t2k < NT) STAGE_A(0, t2k);  // P4
    MFMA16(1, 0, b0);
    if (t2k < NT) { asm volatile("s_waitcnt vmcnt(4)" ::: "memory"); }
    else          { asm volatile("s_waitcnt vmcnt(0)" ::: "memory"); }
    BAR();
    if (t2k < NT) STAGE_B(0, t2k);  // P5
    READ_A(0, 1);
    READ_B(b0, 0, 1);
    BAR();
    MFMA16(0, 0, b0);
    READ_B(b1, 1, 1);           // P6
    BAR();
    MFMA16(0, 1, b1);
    READ_A(1, 1);               // P7
    BAR();
    MFMA16(1, 1, b1);
    if (t3k < NT) STAGE_A(1, t3k);  // P8
    MFMA16(1, 0, b0);
    if (t3k < NT) { asm volatile("s_waitcnt vmcnt(4)" ::: "memory"); }
    else          { asm volatile("s_waitcnt vmcnt(0)" ::: "memory"); }
    BAR();
  }

#pragma unroll
  for (int mi = 0; mi < 8; mi++) {
#pragma unroll
    for (int r = 0; r < 4; r++) {
      const int row = m0 + wm + mi * 16 + quad * 4 + r;
      float hsv = 0.f;
      if (OUT_MODE == 1) hsv = hs[row];
#pragma unroll
      for (int ni = 0; ni < 4; ni++) {
        const int col = n0 + wn + ni * 16 + l15;
        const long o = (long)row * N + col;
        float v = acc[mi][ni][r];
        if (OUT_MODE == 0) {
          ((bf16_t*)outp)[o] = (bf16_t)v;
        } else if (OUT_MODE == 1) {
          float xv = (float)x1[(long)row * DM + col];
          float zv = (float)xz[(long)row * 1536 + DM + col];
          float yv = v * hsv + Dp[col] * xv;
          yv *= zv / (1.f + __expf(-zv));
          ((bf16_t*)outp)[o] = (bf16_t)yv;
        } else {
          ((float*)outp)[o] = v + res[o];
        }
      }
    }
  }
#undef STAGE_A
#undef STAGE_B
#undef READ_A
#undef READ_B
#undef MFMA16
#undef BAR
}

// ===== 256x128 8-phase MFMA GEMM, COUNTED vmcnt (GEMM2/GEMM3) =====
// Parameter variant of gemm256 (same phase/sync/gate skeleton, same swizzle):
// 8 waves as 4M x 2N, wave-tile 64x64, acc 4x4. LDS 96 KB (A 2x32KB, B 2x16KB).
// Grid (M/256)*(N/128) = 768 blocks = 3.0 exact rounds at 1 block/CU.
// Gates: steady state leaves the 4 newest A-loads in flight -> vmcnt(4).
template <int OUT_MODE>
__global__ __launch_bounds__(512, 2)
void gemm256x128_kernel(const bf16_t* __restrict__ A, const bf16_t* __restrict__ BT,
                        void* __restrict__ outp, const float* __restrict__ res,
                        const bf16_t* __restrict__ x1, const bf16_t* __restrict__ xz,
                        const float* __restrict__ hs, const float* __restrict__ Dp,
                        int M, int N, int K) {
  __shared__ __align__(16) bf16_t As[2][256 * 64];  // 64 KB
  __shared__ __align__(16) bf16_t Bs[2][128 * 64];  // 32 KB

  const int nby = N >> 7;                     // N/128
  const int nwg = (M >> 8) * nby;
  const int cpx = nwg >> 3;
  const int wg = blockIdx.x;
  const int swz = (wg & 7) * cpx + (wg >> 3); // bijective (nwg % 8 == 0)
  const int bx = swz / nby;
  const int by = swz - bx * nby;
  const int m0 = bx << 8;
  const int n0 = by << 7;

  const int t = threadIdx.x;
  const int lane = t & 63;
  const int wave = t >> 6;
  const int wm = (wave >> 1) * 64;            // 4 M-waves
  const int wn = (wave & 1) * 64;             // 2 N-waves
  const int l15 = lane & 15;
  const int quad = lane >> 4;

  const int sx0 = (((0 * 4) + quad) ^ (lane & 7)) * 8;
  const int sx1 = (((1 * 4) + quad) ^ (lane & 7)) * 8;

  const int srow = lane >> 3;
  const int scol = (((lane & 7) ^ ((lane >> 3) & 7))) * 8;

  f32x4 acc[4][4] = {};
  bf16x8 a[2][2], b0[2][2], b1[2][2];

  const bf16_t* Abase = A + (long)m0 * K + scol;
  const bf16_t* Bbase = BT + (long)n0 * K + scol;

#define S2A(buf, kt) do {                                                   \
    const long kk_ = (long)(kt) * 64;                                       \
    _Pragma("unroll")                                                       \
    for (int h_ = 0; h_ < 2; h_++) {                                        \
      _Pragma("unroll")                                                     \
      for (int j_ = 0; j_ < 2; j_++) {                                      \
        const int rowl_ = h_ * 128 + wave * 16 + j_ * 8;                    \
        load16_to_lds(Abase + (long)(rowl_ + srow) * K + kk_,               \
                      &As[buf][rowl_ * 64]);                                \
      } } } while (0)

#define S2B(buf, kt) do {                                                   \
    const long kk_ = (long)(kt) * 64;                                       \
    _Pragma("unroll")                                                       \
    for (int j_ = 0; j_ < 2; j_++) {                                        \
      const int rowl_ = wave * 16 + j_ * 8;                                 \
      load16_to_lds(Bbase + (long)(rowl_ + srow) * K + kk_,                 \
                    &Bs[buf][rowl_ * 64]);                                  \
    } } while (0)

#define R2A(qm, buf) do {                                                   \
    _Pragma("unroll")                                                       \
    for (int mi_ = 0; mi_ < 2; mi_++) {                                     \
      const bf16_t* p_ = &As[buf][(wm + (qm) * 32 + mi_ * 16 + l15) * 64];  \
      a[mi_][0] = *(const bf16x8*)(p_ + sx0);                               \
      a[mi_][1] = *(const bf16x8*)(p_ + sx1);                               \
    } } while (0)

#define R2B(dst, qn, buf) do {                                              \
    _Pragma("unroll")                                                       \
    for (int ni_ = 0; ni_ < 2; ni_++) {                                     \
      const bf16_t* p_ = &Bs[buf][(wn + (qn) * 32 + ni_ * 16 + l15) * 64];  \
      dst[ni_][0] = *(const bf16x8*)(p_ + sx0);                             \
      dst[ni_][1] = *(const bf16x8*)(p_ + sx1);                             \
    } } while (0)

#define M8(qm, qn, breg) do {                                               \
    __builtin_amdgcn_s_setprio(1);                                          \
    _Pragma("unroll")                                                       \
    for (int mi_ = 0; mi_ < 2; mi_++) {                                     \
      _Pragma("unroll")                                                     \
      for (int ni_ = 0; ni_ < 2; ni_++) {                                   \
        acc[(qm) * 2 + mi_][(qn) * 2 + ni_] =                               \
            __builtin_amdgcn_mfma_f32_16x16x32_bf16(                        \
                a[mi_][0], breg[ni_][0],                                    \
                acc[(qm) * 2 + mi_][(qn) * 2 + ni_], 0, 0, 0);              \
        acc[(qm) * 2 + mi_][(qn) * 2 + ni_] =                               \
            __builtin_amdgcn_mfma_f32_16x16x32_bf16(                        \
                a[mi_][1], breg[ni_][1],                                    \
                acc[(qm) * 2 + mi_][(qn) * 2 + ni_], 0, 0, 0);              \
      } }                                                                   \
    __builtin_amdgcn_s_setprio(0);                                          \
  } while (0)

#define BAR2() do { asm volatile("" ::: "memory");                          \
    __builtin_amdgcn_s_barrier();                                           \
    asm volatile("" ::: "memory"); } while (0)

  const int NT = K >> 6;
  const int NI = NT >> 1;

  // prologue: tile0 A+B -> buf0 (6 loads), tile1 A -> buf1 (4)
  S2A(0, 0);
  S2B(0, 0);
  S2A(1, 1);
  asm volatile("s_waitcnt vmcnt(4)" ::: "memory");  // tile0's 6 landed
  BAR2();

  for (int it = 0; it < NI; ++it) {
    const int t1k = 2 * it + 1;
    const int t2k = 2 * it + 2;
    const int t3k = 2 * it + 3;
    S2B(1, t1k);                // P1
    R2A(0, 0);
    R2B(b0, 0, 0);
    BAR2();
    M8(0, 0, b0);
    R2B(b1, 1, 0);              // P2
    BAR2();
    M8(0, 1, b1);
    R2A(1, 0);                  // P3 (last buf0 reads)
    BAR2();
    M8(1, 1, b1);
    if (t2k < NT) S2A(0, t2k);  // P4
    M8(1, 0, b0);
    if (t2k < NT) { asm volatile("s_waitcnt vmcnt(4)" ::: "memory"); }
    else          { asm volatile("s_waitcnt vmcnt(0)" ::: "memory"); }
    BAR2();
    if (t2k < NT) S2B(0, t2k);  // P5
    R2A(0, 1);
    R2B(b0, 0, 1);
    BAR2();
    M8(0, 0, b0);
    R2B(b1, 1, 1);              // P6
    BAR2();
    M8(0, 1, b1);
    R2A(1, 1);                  // P7 (last buf1 reads)
    BAR2();
    M8(1, 1, b1);
    if (t3k < NT) S2A(1, t3k);  // P8
    M8(1, 0, b0);
    if (t3k < NT) { asm volatile("s_waitcnt vmcnt(4)" ::: "memory"); }
    else          { asm volatile("s_waitcnt vmcnt(0)" ::: "memory"); }
    BAR2();
  }

#pragma unroll
  for (int mi = 0; mi < 4; mi++) {
#pragma unroll
    for (int r = 0; r < 4; r++) {
      const int row = m0 + wm + mi * 16 + quad * 4 + r;
      float hsv = 0.f;
      if (OUT_MODE == 1) hsv = hs[row];
#pragma unroll
      for (int ni = 0; ni < 4; ni++) {
        const int col = n0 + wn + ni * 16 + l15;
        const long o = (long)row * N + col;
        float v = acc[mi][ni][r];
        if (OUT_MODE == 0) {
          ((bf16_t*)outp)[o] = (bf16_t)v;
        } else if (OUT_MODE == 1) {
          float xv = (float)x1[(long)row * DM + col];
          float zv = (float)xz[(long)row * 1536 + DM + col];
          float yv = v * hsv + Dp[col] * xv;
          yv *= zv / (1.f + __expf(-zv));
          ((bf16_t*)outp)[o] = (bf16_t)yv;
        } else {
          ((float*)outp)[o] = v + res[o];
        }
      }
    }
  }
#undef S2A
#undef S2B
#undef R2A
#undef R2B
#undef M8
#undef BAR2
}

// ---------------- launch ----------------
extern "C" void kernel_launch(void* const* d_in, const int* in_sizes, int n_in,
                              void* d_out, int out_size, void* d_ws, size_t ws_size,
                              hipStream_t stream) {
  const float* x      = (const float*)d_in[0];
  const float* W_in   = (const float*)d_in[1];
  const float* conv_w = (const float*)d_in[2];
  const float* W_x    = (const float*)d_in[3];
  const float* A_log  = (const float*)d_in[4];
  const float* Dp     = (const float*)d_in[5];
  const float* W_out  = (const float*)d_in[6];
  const float* gamma  = (const float*)d_in[7];
  const float* beta   = (const float*)d_in[8];
  float* out = (float*)d_out;

  char* ws = (char*)d_ws;
  bf16_t* w_in_T  = (bf16_t*)(ws + 0);          // 1536x768 bf16
  bf16_t* w_c_T   = (bf16_t*)(ws + 2359296);    //  768x768 bf16
  bf16_t* w_out_T = (bf16_t*)(ws + 3538944);    //  768x768 bf16
  float*  a_vec   = (float*)(ws + 4718592);
  float*  b_vec   = (float*)(ws + 4721664);
  float*  hs      = (float*)(ws + 4724736);     // 32768 f32
  bf16_t* xn      = (bf16_t*)(ws + 4855808);    // 32768x768 bf16 (reused as y)
  bf16_t* xz      = (bf16_t*)(ws + 55187456);   // 32768x1536 bf16
  bf16_t* x1      = (bf16_t*)(ws + 155850752);  // 32768x768 bf16
  bf16_t* y       = xn;

  // fused prep (R7-verified): transposes + ab + layernorm
  prep_kernel<<<dim3(17411), 256, 0, stream>>>(
      W_in, W_x, W_out, A_log, x, gamma, beta,
      w_in_T, w_c_T, w_out_T, a_vec, b_vec, xn);

  gemm256_kernel<0><<<dim3((TOKENS / 256) * (1536 / 256)), 512, 0, stream>>>(
      xn, w_in_T, (void*)xz, nullptr, nullptr, nullptr, nullptr, nullptr,
      TOKENS, 1536, 768);

  conv_kernel<<<dim3(TOKENS / 4), 256, 0, stream>>>(xz, conv_w, a_vec, b_vec, x1, hs);

  gemm256x128_kernel<1><<<dim3((TOKENS / 256) * (768 / 128)), 512, 0, stream>>>(
      x1, w_c_T, (void*)y, nullptr, x1, xz, hs, Dp,
      TOKENS, 768, 768);

  gemm256x128_kernel<2><<<dim3((TOKENS / 256) * (768 / 128)), 512, 0, stream>>>(
      y, w_out_T, (void*)out, x, nullptr, nullptr, nullptr, nullptr,
      TOKENS, 768, 768);
}

// Round 12
// 460.536 us; speedup vs baseline: 1.1516x; 1.0257x over previous
//
#include <hip/hip_runtime.h>

typedef __bf16 bf16_t;
typedef __bf16 bf16x8 __attribute__((ext_vector_type(8)));
typedef __bf16 bf16x4 __attribute__((ext_vector_type(4)));
typedef float f32x4 __attribute__((ext_vector_type(4)));

#define DM 768
#define SEQ_LEN 4096
#define TOKENS 32768

// async 16B global -> LDS (wave-uniform LDS base + lane*16)
__device__ __forceinline__ void load16_to_lds(const void* g, void* l) {
  __builtin_amdgcn_global_load_lds(
      (const __attribute__((address_space(1))) unsigned int*)g,
      (__attribute__((address_space(3))) unsigned int*)l, 16, 0, 0);
}

// ============ fused prep: 3 TILED weight transposes + ab + layernorm ======
// blocks [0,288): W_in^T tiles ; [288,432): w_c^T ; [432,576): w_out^T ;
// [576,579): ab ; [579,8771): layernorm. All segments independent.
// Transpose: 64x64 f32 tile via LDS (pad 65) -> coalesced read AND write.
// (R11's prep did stride-6KB scalar reads: 1 cacheline per element, ~150 MB
//  effective for 9.4 MB of weights. This cuts it to ~2x data size.)
__global__ __launch_bounds__(256)
void prep_kernel(const float* __restrict__ W_in, const float* __restrict__ W_x,
                 const float* __restrict__ W_out, const float* __restrict__ A_log,
                 const float* __restrict__ x, const float* __restrict__ gamma,
                 const float* __restrict__ beta,
                 bf16_t* __restrict__ w_in_T, bf16_t* __restrict__ w_c_T,
                 bf16_t* __restrict__ w_out_T, float* __restrict__ a_vec,
                 float* __restrict__ b_vec, bf16_t* __restrict__ xn) {
  const int bid = blockIdx.x;
  const int tid = threadIdx.x;
  if (bid < 576) {
    __shared__ float tile[64][65];
    const float* src;
    bf16_t* dst;
    int stride, off, ki, ni;
    if (bid < 288) {        // W_in [768][1536] -> w_in_T [1536][768]
      src = W_in; dst = w_in_T; stride = 1536; off = 0;
      ki = bid / 24; ni = bid % 24;
    } else if (bid < 432) { // W_x [768][784] cols 16.. -> w_c_T [768][768]
      int t = bid - 288;
      src = W_x; dst = w_c_T; stride = 784; off = 16;
      ki = t / 12; ni = t % 12;
    } else {                // W_out [768][768] -> w_out_T [768][768]
      int t = bid - 432;
      src = W_out; dst = w_out_T; stride = 768; off = 0;
      ki = t / 12; ni = t % 12;
    }
    const int k0 = ki * 64, n0 = ni * 64;
    const int rr = tid >> 6, cc = tid & 63;
#pragma unroll
    for (int i = 0; i < 16; i++) {
      int r = i * 4 + rr;                       // coalesced: consecutive cc
      tile[r][cc] = src[(long)(k0 + r) * stride + off + n0 + cc];
    }
    __syncthreads();
#pragma unroll
    for (int i = 0; i < 16; i++) {
      int n = i * 4 + rr;                       // coalesced: consecutive cc=k
      dst[(long)(n0 + n) * 768 + k0 + cc] = (bf16_t)tile[cc][n];
    }
  } else if (bid < 579) {                       // ab
    int k = (bid - 576) * 256 + tid;
    if (k < DM) {
      float a = 0.f, b = 0.f;
#pragma unroll
      for (int d = 0; d < 16; d++) {
        a -= __expf(A_log[k * 16 + d]);
        b += W_x[(long)k * 784 + d];
      }
      a_vec[k] = a;
      b_vec[k] = b;
    }
  } else {                                      // layernorm (token per wave)
    const int tok = (bid - 579) * 4 + (tid >> 6);
    const int lane = tid & 63;
    const float4* xr = (const float4*)(x + (long)tok * DM);
    float4 v0 = xr[lane], v1 = xr[lane + 64], v2 = xr[lane + 128];
    float s = v0.x + v0.y + v0.z + v0.w + v1.x + v1.y + v1.z + v1.w +
              v2.x + v2.y + v2.z + v2.w;
    float ss = v0.x * v0.x + v0.y * v0.y + v0.z * v0.z + v0.w * v0.w +
               v1.x * v1.x + v1.y * v1.y + v1.z * v1.z + v1.w * v1.w +
               v2.x * v2.x + v2.y * v2.y + v2.z * v2.z + v2.w * v2.w;
    for (int o = 1; o < 64; o <<= 1) { s += __shfl_xor(s, o); ss += __shfl_xor(ss, o); }
    float mu = s * (1.0f / DM);
    float var = ss * (1.0f / DM) - mu * mu;
    float inv = rsqrtf(var + 1e-5f);
    const float4* g4 = (const float4*)gamma;
    const float4* b4 = (const float4*)beta;
    bf16_t* xo = xn + (long)tok * DM;
#pragma unroll
    for (int i = 0; i < 3; i++) {
      float4 v = (i == 0) ? v0 : (i == 1) ? v1 : v2;
      float4 g = g4[lane + 64 * i], b = b4[lane + 64 * i];
      bf16x4 o;
      o[0] = (bf16_t)((v.x - mu) * inv * g.x + b.x);
      o[1] = (bf16_t)((v.y - mu) * inv * g.y + b.y);
      o[2] = (bf16_t)((v.z - mu) * inv * g.z + b.z);
      o[3] = (bf16_t)((v.w - mu) * inv * g.w + b.w);
      *(bf16x4*)(xo + lane * 4 + i * 256) = o;
    }
  }
}

// ---------------- depthwise causal conv (4 taps) + hs (token per wave) -------
__global__ __launch_bounds__(256)
void conv_kernel(const bf16_t* __restrict__ xz, const float* __restrict__ conv_w,
                 const float* __restrict__ a_vec, const float* __restrict__ b_vec,
                 bf16_t* __restrict__ x1, float* __restrict__ hs) {
  const int tok = blockIdx.x * 4 + (threadIdx.x >> 6);
  const int lane = threadIdx.x & 63;
  const int l = tok & (SEQ_LEN - 1);
  const bf16_t* base = xz + (long)tok * 1536;
  const float4* w4 = (const float4*)conv_w;
  float s = 0.f, sa = 0.f, sb = 0.f;

  {
    const int c0 = lane * 8;
    bf16x8 cur = *(const bf16x8*)(base + c0);
    bf16x8 p1 = {}, p2 = {}, p3 = {};
    if (l >= 1) p1 = *(const bf16x8*)(base + c0 - 1536);
    if (l >= 2) p2 = *(const bf16x8*)(base + c0 - 2 * 1536);
    if (l >= 3) p3 = *(const bf16x8*)(base + c0 - 3 * 1536);
    bf16x8 o;
#pragma unroll
    for (int j = 0; j < 8; j++) {
      float4 w = w4[c0 + j];
      float acc = w.w * (float)cur[j] + w.z * (float)p1[j] +
                  w.y * (float)p2[j] + w.x * (float)p3[j];
      bf16_t xb = (bf16_t)acc;
      o[j] = xb;
      float xv = (float)xb;
      s += xv; sa += xv * a_vec[c0 + j]; sb += xv * b_vec[c0 + j];
    }
    *(bf16x8*)(x1 + (long)tok * DM + c0) = o;
  }
  {
    const int c0 = 512 + lane * 4;
    bf16x4 cur = *(const bf16x4*)(base + c0);
    bf16x4 p1 = {}, p2 = {}, p3 = {};
    if (l >= 1) p1 = *(const bf16x4*)(base + c0 - 1536);
    if (l >= 2) p2 = *(const bf16x4*)(base + c0 - 2 * 1536);
    if (l >= 3) p3 = *(const bf16x4*)(base + c0 - 3 * 1536);
    bf16x4 o;
#pragma unroll
    for (int j = 0; j < 4; j++) {
      float4 w = w4[c0 + j];
      float acc = w.w * (float)cur[j] + w.z * (float)p1[j] +
                  w.y * (float)p2[j] + w.x * (float)p3[j];
      bf16_t xb = (bf16_t)acc;
      o[j] = xb;
      float xv = (float)xb;
      s += xv; sa += xv * a_vec[c0 + j]; sb += xv * b_vec[c0 + j];
    }
    *(bf16x4*)(x1 + (long)tok * DM + c0) = o;
  }
  for (int o = 1; o < 64; o <<= 1) {
    s += __shfl_xor(s, o); sa += __shfl_xor(sa, o); sb += __shfl_xor(sb, o);
  }
  if (lane == 0) hs[tok] = sa + s * sb;
}

// ========= 256x256 8-phase MFMA GEMM, COUNTED vmcnt (GEMM1) =========
// Measured R7/R11: ~92 us, MfmaUtil 34.5%, conflicts 0, FETCH ideal.
template <int OUT_MODE>
__global__ __launch_bounds__(512, 2)
void gemm256_kernel(const bf16_t* __restrict__ A, const bf16_t* __restrict__ BT,
                    void* __restrict__ outp, const float* __restrict__ res,
                    const bf16_t* __restrict__ x1, const bf16_t* __restrict__ xz,
                    const float* __restrict__ hs, const float* __restrict__ Dp,
                    int M, int N, int K) {
  __shared__ __align__(16) bf16_t As[2][256 * 64];
  __shared__ __align__(16) bf16_t Bs[2][256 * 64];

  const int nby = N >> 8;
  const int nwg = (M >> 8) * nby;
  const int cpx = nwg >> 3;
  const int wg = blockIdx.x;
  const int swz = (wg & 7) * cpx + (wg >> 3);
  const int bx = swz / nby;
  const int by = swz - bx * nby;
  const int m0 = bx << 8;
  const int n0 = by << 8;

  const int t = threadIdx.x;
  const int lane = t & 63;
  const int wave = t >> 6;
  const int wm = (wave >> 2) * 128;
  const int wn = (wave & 3) * 64;
  const int l15 = lane & 15;
  const int quad = lane >> 4;

  const int sx0 = (((0 * 4) + quad) ^ (lane & 7)) * 8;
  const int sx1 = (((1 * 4) + quad) ^ (lane & 7)) * 8;

  const int srow = lane >> 3;
  const int scol = (((lane & 7) ^ ((lane >> 3) & 7))) * 8;

  f32x4 acc[8][4] = {};
  bf16x8 a[4][2], b0[2][2], b1[2][2];

  const bf16_t* Abase = A + (long)m0 * K + scol;
  const bf16_t* Bbase = BT + (long)n0 * K + scol;

#define STAGE_A(buf, kt) do {                                               \
    const long kk_ = (long)(kt) * 64;                                       \
    _Pragma("unroll")                                                       \
    for (int h_ = 0; h_ < 2; h_++) {                                        \
      _Pragma("unroll")                                                     \
      for (int j_ = 0; j_ < 2; j_++) {                                      \
        const int rowl_ = h_ * 128 + wave * 16 + j_ * 8;                    \
        load16_to_lds(Abase + (long)(rowl_ + srow) * K + kk_,               \
                      &As[buf][rowl_ * 64]);                                \
      } } } while (0)

#define STAGE_B(buf, kt) do {                                               \
    const long kk_ = (long)(kt) * 64;                                       \
    _Pragma("unroll")                                                       \
    for (int h_ = 0; h_ < 2; h_++) {                                        \
      _Pragma("unroll")                                                     \
      for (int j_ = 0; j_ < 2; j_++) {                                      \
        const int rowl_ = h_ * 128 + wave * 16 + j_ * 8;                    \
        load16_to_lds(Bbase + (long)(rowl_ + srow) * K + kk_,               \
                      &Bs[buf][rowl_ * 64]);                                \
      } } } while (0)

#define READ_A(qm, buf) do {                                                \
    _Pragma("unroll")                                                       \
    for (int mi_ = 0; mi_ < 4; mi_++) {                                     \
      const bf16_t* p_ = &As[buf][(wm + (qm) * 64 + mi_ * 16 + l15) * 64];  \
      a[mi_][0] = *(const bf16x8*)(p_ + sx0);                               \
      a[mi_][1] = *(const bf16x8*)(p_ + sx1);                               \
    } } while (0)

#define READ_B(dst, qn, buf) do {                                           \
    _Pragma("unroll")                                                       \
    for (int ni_ = 0; ni_ < 2; ni_++) {                                     \
      const bf16_t* p_ = &Bs[buf][(wn + (qn) * 32 + ni_ * 16 + l15) * 64];  \
      dst[ni_][0] = *(const bf16x8*)(p_ + sx0);                             \
      dst[ni_][1] = *(const bf16x8*)(p_ + sx1);                             \
    } } while (0)

#define MFMA16(qm, qn, breg) do {                                           \
    __builtin_amdgcn_s_setprio(1);                                          \
    _Pragma("unroll")                                                       \
    for (int mi_ = 0; mi_ < 4; mi_++) {                                     \
      _Pragma("unroll")                                                     \
      for (int ni_ = 0; ni_ < 2; ni_++) {                                   \
        acc[(qm) * 4 + mi_][(qn) * 2 + ni_] =                               \
            __builtin_amdgcn_mfma_f32_16x16x32_bf16(                        \
                a[mi_][0], breg[ni_][0],                                    \
                acc[(qm) * 4 + mi_][(qn) * 2 + ni_], 0, 0, 0);              \
        acc[(qm) * 4 + mi_][(qn) * 2 + ni_] =                               \
            __builtin_amdgcn_mfma_f32_16x16x32_bf16(                        \
                a[mi_][1], breg[ni_][1],                                    \
                acc[(qm) * 4 + mi_][(qn) * 2 + ni_], 0, 0, 0);              \
      } }                                                                   \
    __builtin_amdgcn_s_setprio(0);                                          \
  } while (0)

#define BAR() do { asm volatile("" ::: "memory");                           \
    __builtin_amdgcn_s_barrier();                                           \
    asm volatile("" ::: "memory"); } while (0)

  const int NT = K >> 6;
  const int NI = NT >> 1;

  STAGE_A(0, 0);
  STAGE_B(0, 0);
  STAGE_A(1, 1);
  asm volatile("s_waitcnt vmcnt(4)" ::: "memory");
  BAR();

  for (int it = 0; it < NI; ++it) {
    const int t1k = 2 * it + 1;
    const int t2k = 2 * it + 2;
    const int t3k = 2 * it + 3;
    STAGE_B(1, t1k);            // P1
    READ_A(0, 0);
    READ_B(b0, 0, 0);
    BAR();
    MFMA16(0, 0, b0);
    READ_B(b1, 1, 0);           // P2
    BAR();
    MFMA16(0, 1, b1);
    READ_A(1, 0);               // P3
    BAR();
    MFMA16(1, 1, b1);
    if (t2k < NT) STAGE_A(0, t2k);  // P4
    MFMA16(1, 0, b0);
    if (t2k < NT) { asm volatile("s_waitcnt vmcnt(4)" ::: "memory"); }
    else          { asm volatile("s_waitcnt vmcnt(0)" ::: "memory"); }
    BAR();
    if (t2k < NT) STAGE_B(0, t2k);  // P5
    READ_A(0, 1);
    READ_B(b0, 0, 1);
    BAR();
    MFMA16(0, 0, b0);
    READ_B(b1, 1, 1);           // P6
    BAR();
    MFMA16(0, 1, b1);
    READ_A(1, 1);               // P7
    BAR();
    MFMA16(1, 1, b1);
    if (t3k < NT) STAGE_A(1, t3k);  // P8
    MFMA16(1, 0, b0);
    if (t3k < NT) { asm volatile("s_waitcnt vmcnt(4)" ::: "memory"); }
    else          { asm volatile("s_waitcnt vmcnt(0)" ::: "memory"); }
    BAR();
  }

#pragma unroll
  for (int mi = 0; mi < 8; mi++) {
#pragma unroll
    for (int r = 0; r < 4; r++) {
      const int row = m0 + wm + mi * 16 + quad * 4 + r;
      float hsv = 0.f;
      if (OUT_MODE == 1) hsv = hs[row];
#pragma unroll
      for (int ni = 0; ni < 4; ni++) {
        const int col = n0 + wn + ni * 16 + l15;
        const long o = (long)row * N + col;
        float v = acc[mi][ni][r];
        if (OUT_MODE == 0) {
          ((bf16_t*)outp)[o] = (bf16_t)v;
        } else if (OUT_MODE == 1) {
          float xv = (float)x1[(long)row * DM + col];
          float zv = (float)xz[(long)row * 1536 + DM + col];
          float yv = v * hsv + Dp[col] * xv;
          yv *= zv / (1.f + __expf(-zv));
          ((bf16_t*)outp)[o] = (bf16_t)yv;
        } else {
          ((float*)outp)[o] = v + res[o];
        }
      }
    }
  }
#undef STAGE_A
#undef STAGE_B
#undef READ_A
#undef READ_B
#undef MFMA16
#undef BAR
}

// ===== 256x128 8-phase MFMA GEMM, COUNTED vmcnt (GEMM2/GEMM3) =====
// R11-verified (passed; both dispatches < 91 us).
template <int OUT_MODE>
__global__ __launch_bounds__(512, 2)
void gemm256x128_kernel(const bf16_t* __restrict__ A, const bf16_t* __restrict__ BT,
                        void* __restrict__ outp, const float* __restrict__ res,
                        const bf16_t* __restrict__ x1, const bf16_t* __restrict__ xz,
                        const float* __restrict__ hs, const float* __restrict__ Dp,
                        int M, int N, int K) {
  __shared__ __align__(16) bf16_t As[2][256 * 64];  // 64 KB
  __shared__ __align__(16) bf16_t Bs[2][128 * 64];  // 32 KB

  const int nby = N >> 7;                     // N/128
  const int nwg = (M >> 8) * nby;
  const int cpx = nwg >> 3;
  const int wg = blockIdx.x;
  const int swz = (wg & 7) * cpx + (wg >> 3); // bijective (nwg % 8 == 0)
  const int bx = swz / nby;
  const int by = swz - bx * nby;
  const int m0 = bx << 8;
  const int n0 = by << 7;

  const int t = threadIdx.x;
  const int lane = t & 63;
  const int wave = t >> 6;
  const int wm = (wave >> 1) * 64;            // 4 M-waves
  const int wn = (wave & 1) * 64;             // 2 N-waves
  const int l15 = lane & 15;
  const int quad = lane >> 4;

  const int sx0 = (((0 * 4) + quad) ^ (lane & 7)) * 8;
  const int sx1 = (((1 * 4) + quad) ^ (lane & 7)) * 8;

  const int srow = lane >> 3;
  const int scol = (((lane & 7) ^ ((lane >> 3) & 7))) * 8;

  f32x4 acc[4][4] = {};
  bf16x8 a[2][2], b0[2][2], b1[2][2];

  const bf16_t* Abase = A + (long)m0 * K + scol;
  const bf16_t* Bbase = BT + (long)n0 * K + scol;

#define S2A(buf, kt) do {                                                   \
    const long kk_ = (long)(kt) * 64;                                       \
    _Pragma("unroll")                                                       \
    for (int h_ = 0; h_ < 2; h_++) {                                        \
      _Pragma("unroll")                                                     \
      for (int j_ = 0; j_ < 2; j_++) {                                      \
        const int rowl_ = h_ * 128 + wave * 16 + j_ * 8;                    \
        load16_to_lds(Abase + (long)(rowl_ + srow) * K + kk_,               \
                      &As[buf][rowl_ * 64]);                                \
      } } } while (0)

#define S2B(buf, kt) do {                                                   \
    const long kk_ = (long)(kt) * 64;                                       \
    _Pragma("unroll")                                                       \
    for (int j_ = 0; j_ < 2; j_++) {                                        \
      const int rowl_ = wave * 16 + j_ * 8;                                 \
      load16_to_lds(Bbase + (long)(rowl_ + srow) * K + kk_,                 \
                    &Bs[buf][rowl_ * 64]);                                  \
    } } while (0)

#define R2A(qm, buf) do {                                                   \
    _Pragma("unroll")                                                       \
    for (int mi_ = 0; mi_ < 2; mi_++) {                                     \
      const bf16_t* p_ = &As[buf][(wm + (qm) * 32 + mi_ * 16 + l15) * 64];  \
      a[mi_][0] = *(const bf16x8*)(p_ + sx0);                               \
      a[mi_][1] = *(const bf16x8*)(p_ + sx1);                               \
    } } while (0)

#define R2B(dst, qn, buf) do {                                              \
    _Pragma("unroll")                                                       \
    for (int ni_ = 0; ni_ < 2; ni_++) {                                     \
      const bf16_t* p_ = &Bs[buf][(wn + (qn) * 32 + ni_ * 16 + l15) * 64];  \
      dst[ni_][0] = *(const bf16x8*)(p_ + sx0);                             \
      dst[ni_][1] = *(const bf16x8*)(p_ + sx1);                             \
    } } while (0)

#define M8(qm, qn, breg) do {                                               \
    __builtin_amdgcn_s_setprio(1);                                          \
    _Pragma("unroll")                                                       \
    for (int mi_ = 0; mi_ < 2; mi_++) {                                     \
      _Pragma("unroll")                                                     \
      for (int ni_ = 0; ni_ < 2; ni_++) {                                   \
        acc[(qm) * 2 + mi_][(qn) * 2 + ni_] =                               \
            __builtin_amdgcn_mfma_f32_16x16x32_bf16(                        \
                a[mi_][0], breg[ni_][0],                                    \
                acc[(qm) * 2 + mi_][(qn) * 2 + ni_], 0, 0, 0);              \
        acc[(qm) * 2 + mi_][(qn) * 2 + ni_] =                               \
            __builtin_amdgcn_mfma_f32_16x16x32_bf16(                        \
                a[mi_][1], breg[ni_][1],                                    \
                acc[(qm) * 2 + mi_][(qn) * 2 + ni_], 0, 0, 0);              \
      } }                                                                   \
    __builtin_amdgcn_s_setprio(0);                                          \
  } while (0)

#define BAR2() do { asm volatile("" ::: "memory");                          \
    __builtin_amdgcn_s_barrier();                                           \
    asm volatile("" ::: "memory"); } while (0)

  const int NT = K >> 6;
  const int NI = NT >> 1;

  // prologue: tile0 A+B -> buf0 (6 loads), tile1 A -> buf1 (4)
  S2A(0, 0);
  S2B(0, 0);
  S2A(1, 1);
  asm volatile("s_waitcnt vmcnt(4)" ::: "memory");  // tile0's 6 landed
  BAR2();

  for (int it = 0; it < NI; ++it) {
    const int t1k = 2 * it + 1;
    const int t2k = 2 * it + 2;
    const int t3k = 2 * it + 3;
    S2B(1, t1k);                // P1
    R2A(0, 0);
    R2B(b0, 0, 0);
    BAR2();
    M8(0, 0, b0);
    R2B(b1, 1, 0);              // P2
    BAR2();
    M8(0, 1, b1);
    R2A(1, 0);                  // P3 (last buf0 reads)
    BAR2();
    M8(1, 1, b1);
    if (t2k < NT) S2A(0, t2k);  // P4
    M8(1, 0, b0);
    if (t2k < NT) { asm volatile("s_waitcnt vmcnt(4)" ::: "memory"); }
    else          { asm volatile("s_waitcnt vmcnt(0)" ::: "memory"); }
    BAR2();
    if (t2k < NT) S2B(0, t2k);  // P5
    R2A(0, 1);
    R2B(b0, 0, 1);
    BAR2();
    M8(0, 0, b0);
    R2B(b1, 1, 1);              // P6
    BAR2();
    M8(0, 1, b1);
    R2A(1, 1);                  // P7 (last buf1 reads)
    BAR2();
    M8(1, 1, b1);
    if (t3k < NT) S2A(1, t3k);  // P8
    M8(1, 0, b0);
    if (t3k < NT) { asm volatile("s_waitcnt vmcnt(4)" ::: "memory"); }
    else          { asm volatile("s_waitcnt vmcnt(0)" ::: "memory"); }
    BAR2();
  }

#pragma unroll
  for (int mi = 0; mi < 4; mi++) {
#pragma unroll
    for (int r = 0; r < 4; r++) {
      const int row = m0 + wm + mi * 16 + quad * 4 + r;
      float hsv = 0.f;
      if (OUT_MODE == 1) hsv = hs[row];
#pragma unroll
      for (int ni = 0; ni < 4; ni++) {
        const int col = n0 + wn + ni * 16 + l15;
        const long o = (long)row * N + col;
        float v = acc[mi][ni][r];
        if (OUT_MODE == 0) {
          ((bf16_t*)outp)[o] = (bf16_t)v;
        } else if (OUT_MODE == 1) {
          float xv = (float)x1[(long)row * DM + col];
          float zv = (float)xz[(long)row * 1536 + DM + col];
          float yv = v * hsv + Dp[col] * xv;
          yv *= zv / (1.f + __expf(-zv));
          ((bf16_t*)outp)[o] = (bf16_t)yv;
        } else {
          ((float*)outp)[o] = v + res[o];
        }
      }
    }
  }
#undef S2A
#undef S2B
#undef R2A
#undef R2B
#undef M8
#undef BAR2
}

// ---------------- launch ----------------
extern "C" void kernel_launch(void* const* d_in, const int* in_sizes, int n_in,
                              void* d_out, int out_size, void* d_ws, size_t ws_size,
                              hipStream_t stream) {
  const float* x      = (const float*)d_in[0];
  const float* W_in   = (const float*)d_in[1];
  const float* conv_w = (const float*)d_in[2];
  const float* W_x    = (const float*)d_in[3];
  const float* A_log  = (const float*)d_in[4];
  const float* Dp     = (const float*)d_in[5];
  const float* W_out  = (const float*)d_in[6];
  const float* gamma  = (const float*)d_in[7];
  const float* beta   = (const float*)d_in[8];
  float* out = (float*)d_out;

  char* ws = (char*)d_ws;
  bf16_t* w_in_T  = (bf16_t*)(ws + 0);          // 1536x768 bf16
  bf16_t* w_c_T   = (bf16_t*)(ws + 2359296);    //  768x768 bf16
  bf16_t* w_out_T = (bf16_t*)(ws + 3538944);    //  768x768 bf16
  float*  a_vec   = (float*)(ws + 4718592);
  float*  b_vec   = (float*)(ws + 4721664);
  float*  hs      = (float*)(ws + 4724736);     // 32768 f32
  bf16_t* xn      = (bf16_t*)(ws + 4855808);    // 32768x768 bf16 (reused as y)
  bf16_t* xz      = (bf16_t*)(ws + 55187456);   // 32768x1536 bf16
  bf16_t* x1      = (bf16_t*)(ws + 155850752);  // 32768x768 bf16
  bf16_t* y       = xn;

  // fused prep: TILED transposes + ab + layernorm
  prep_kernel<<<dim3(8771), 256, 0, stream>>>(
      W_in, W_x, W_out, A_log, x, gamma, beta,
      w_in_T, w_c_T, w_out_T, a_vec, b_vec, xn);

  gemm256_kernel<0><<<dim3((TOKENS / 256) * (1536 / 256)), 512, 0, stream>>>(
      xn, w_in_T, (void*)xz, nullptr, nullptr, nullptr, nullptr, nullptr,
      TOKENS, 1536, 768);

  conv_kernel<<<dim3(TOKENS / 4), 256, 0, stream>>>(xz, conv_w, a_vec, b_vec, x1, hs);

  gemm256x128_kernel<1><<<dim3((TOKENS / 256) * (768 / 128)), 512, 0, stream>>>(
      x1, w_c_T, (void*)y, nullptr, x1, xz, hs, Dp,
      TOKENS, 768, 768);

  gemm256x128_kernel<2><<<dim3((TOKENS / 256) * (768 / 128)), 512, 0, stream>>>(
      y, w_out_T, (void*)out, x, nullptr, nullptr, nullptr, nullptr,
      TOKENS, 768, 768);
}